// Round 5
// baseline (605.597 us; speedup 1.0000x reference)
//
#include <hip/hip_runtime.h>

// ---------- types ----------
typedef short short8 __attribute__((ext_vector_type(8)));     // 8 bf16 bit-patterns (4 VGPRs) - MFMA A/B frag
typedef float f32x4 __attribute__((ext_vector_type(4)));      // MFMA C/D frag
typedef unsigned short u16x8 __attribute__((ext_vector_type(8)));

#define B_DIM 4096
#define IN_DIM 512
#define H_DIM 1024
#define KCAT 1536   // IN_DIM + H_DIM

__device__ __forceinline__ float bs2f(unsigned short s) {
    return __uint_as_float(((unsigned int)s) << 16);
}
__device__ __forceinline__ unsigned short f2bs(float f) {
    unsigned int u = __float_as_uint(f);
    u += 0x7fff + ((u >> 16) & 1);   // RNE
    return (unsigned short)(u >> 16);
}
__device__ __forceinline__ float sigm(float x) { return 1.0f / (1.0f + __expf(-x)); }
__device__ __forceinline__ float ftanh(float x) { return 1.0f - 2.0f / (__expf(2.0f * x) + 1.0f); }

// ---------- f32 -> bf16 strided row convert: out[r*ld + off + c] = bf16(in[r*width + c]) ----------
__global__ __launch_bounds__(256) void convs(const float* __restrict__ in,
                                             unsigned short* __restrict__ out,
                                             int n, int width, int ld, int off) {
    int i = (blockIdx.x * blockDim.x + threadIdx.x) * 8;
    if (i >= n) return;
    int r = i / width;
    int c = i % width;            // width % 8 == 0 so all 8 stay in-row
    float4 a = *(const float4*)(in + i);
    float4 b = *(const float4*)(in + i + 4);
    u16x8 o;
    o[0] = f2bs(a.x); o[1] = f2bs(a.y); o[2] = f2bs(a.z); o[3] = f2bs(a.w);
    o[4] = f2bs(b.x); o[5] = f2bs(b.y); o[6] = f2bs(b.z); o[7] = f2bs(b.w);
    *(u16x8*)(out + (size_t)r * ld + off + c) = o;
}

// ---------- bias sum + dt ----------
__global__ __launch_bounds__(256) void prep_small(const float* __restrict__ bih,
                                                  const float* __restrict__ bhh,
                                                  const float* __restrict__ ts,
                                                  float* __restrict__ bsum,
                                                  float* __restrict__ dtv,
                                                  int n4h, int nb) {
    int i = blockIdx.x * blockDim.x + threadIdx.x;
    if (i < n4h) bsum[i] = bih[i] + bhh[i];
    if (i < nb)  dtv[i] = ts[2 * i + 1] - ts[2 * i];
}

// ---------- LSTM cell elementwise: c path in f32, h out bf16 (strided), c out f32 ----------
__global__ __launch_bounds__(256) void cellk(const unsigned short* __restrict__ gates, // [B,4H] bf16
                                             const float* __restrict__ c_in,           // [B,H] f32
                                             unsigned short* __restrict__ h_out,       // strided bf16
                                             int h_ld, int h_off,
                                             float* __restrict__ c_out,                // [B,H] f32
                                             int Bn, int Hn) {
    int tid = blockIdx.x * blockDim.x + threadIdx.x;
    long e = (long)tid * 8;
    if (e >= (long)Bn * Hn) return;
    int b = (int)(e / Hn);
    int j = (int)(e % Hn);
    const unsigned short* g0 = gates + (size_t)b * 4 * Hn + j;
    u16x8 gi = *(const u16x8*)(g0);
    u16x8 gf = *(const u16x8*)(g0 + Hn);
    u16x8 gg = *(const u16x8*)(g0 + 2 * Hn);
    u16x8 go = *(const u16x8*)(g0 + 3 * Hn);
    float4 ca = *(const float4*)(c_in + e);
    float4 cb = *(const float4*)(c_in + e + 4);
    float cin[8] = {ca.x, ca.y, ca.z, ca.w, cb.x, cb.y, cb.z, cb.w};
    u16x8 ho;
    float co[8];
    #pragma unroll
    for (int q = 0; q < 8; ++q) {
        float iv = sigm(bs2f(gi[q]));
        float fv = sigm(bs2f(gf[q]));
        float gv = ftanh(bs2f(gg[q]));
        float ov = sigm(bs2f(go[q]));
        float cn = fv * cin[q] + iv * gv;
        float hn = ov * ftanh(cn);
        ho[q] = f2bs(hn);
        co[q] = cn;
    }
    *(u16x8*)(h_out + (size_t)b * h_ld + h_off + j) = ho;
    *(float4*)(c_out + e) = make_float4(co[0], co[1], co[2], co[3]);
    *(float4*)(c_out + e + 4) = make_float4(co[4], co[5], co[6], co[7]);
}

// ---------- GEMM: C[m,n] = sum_k A[m,k]*W[n,k]  (A:[M,K], W:[N,K], both bf16) ----------
// m97 structure: 128x128 tile, BK=32, 4 waves (2x2), 16x16x32 MFMA, global_load_lds w16.
// EPI: 0 = bf16(acc+bias) -> outb                  (gates)
//      1 = bf16(tanh(acc+bias)) -> outb            (RK4 u)
//      2 = k=acc+bias; S=(first?0:S)+cw*k; ynext=bf16(h+alpha*dt*k)
//      3 = k=acc+bias; outf=f32(h + dt/6*(S+k))    (final ht, f32!)
#define BMt 128
#define BNt 128
#define BKt 32

template <int EPI>
__global__ __launch_bounds__(256) void gemm_bt(
    const unsigned short* __restrict__ A,
    const unsigned short* __restrict__ W,
    const int M, const int N, const int K,
    const float* __restrict__ bias,
    unsigned short* __restrict__ outb,
    float* __restrict__ outf,
    const unsigned short* __restrict__ hmat,
    const float* __restrict__ dtv,
    float* __restrict__ S,
    unsigned short* __restrict__ ynext,
    const float alpha, const float cw, const int first) {
    __shared__ unsigned short lA[BMt * BKt];
    __shared__ unsigned short lB[BNt * BKt];
    const int t = threadIdx.x;
    const int lane = t & 63;
    const int wave = t >> 6;
    const int wm = (wave >> 1) * 64;
    const int wn = (wave & 1) * 64;
    const int fr = lane & 15;
    const int kb = lane >> 4;
    const int tile_m = blockIdx.y * BMt;
    const int tile_n = blockIdx.x * BNt;

    f32x4 acc[4][4];
    #pragma unroll
    for (int i = 0; i < 4; ++i)
        #pragma unroll
        for (int j = 0; j < 4; ++j)
            acc[i][j] = (f32x4){0.f, 0.f, 0.f, 0.f};

    const unsigned short* aptr = A + (size_t)tile_m * K;
    const unsigned short* wptr = W + (size_t)tile_n * K;

    for (int k0 = 0; k0 < K; k0 += BKt) {
        #pragma unroll
        for (int j = 0; j < 2; ++j) {
            int idx = j * 256 + t;
            int row = idx >> 2;
            int col = (idx & 3) * 8;
            __builtin_amdgcn_global_load_lds(
                (__attribute__((address_space(1))) void*)(aptr + (size_t)row * K + k0 + col),
                (__attribute__((address_space(3))) void*)(&lA[idx * 8]), 16, 0, 0);
            __builtin_amdgcn_global_load_lds(
                (__attribute__((address_space(1))) void*)(wptr + (size_t)row * K + k0 + col),
                (__attribute__((address_space(3))) void*)(&lB[idx * 8]), 16, 0, 0);
        }
        __syncthreads();
        short8 af[4], bfrag[4];
        #pragma unroll
        for (int i = 0; i < 4; ++i)
            af[i] = *(const short8*)&lA[(wm + i * 16 + fr) * BKt + kb * 8];
        #pragma unroll
        for (int j = 0; j < 4; ++j)
            bfrag[j] = *(const short8*)&lB[(wn + j * 16 + fr) * BKt + kb * 8];
        #pragma unroll
        for (int i = 0; i < 4; ++i)
            #pragma unroll
            for (int j = 0; j < 4; ++j)
                acc[i][j] = __builtin_amdgcn_mfma_f32_16x16x32_bf16(af[i], bfrag[j], acc[i][j], 0, 0, 0);
        __syncthreads();
    }

    // epilogue: D element (col = lane&15 -> n, row = (lane>>4)*4+r -> m)
    #pragma unroll
    for (int i = 0; i < 4; ++i) {
        #pragma unroll
        for (int r = 0; r < 4; ++r) {
            const int m = tile_m + wm + i * 16 + kb * 4 + r;
            float dt = 0.f;
            if (EPI >= 2) dt = dtv[m];
            #pragma unroll
            for (int j = 0; j < 4; ++j) {
                const int n = tile_n + wn + j * 16 + fr;
                const size_t off = (size_t)m * N + n;
                float v = acc[i][j][r];
                if (bias) v += bias[n];
                if (EPI == 0) {
                    outb[off] = f2bs(v);
                } else if (EPI == 1) {
                    outb[off] = f2bs(ftanh(v));
                } else if (EPI == 2) {
                    float hv = bs2f(hmat[off]);
                    float s = first ? 0.f : S[off];
                    S[off] = s + cw * v;
                    ynext[off] = f2bs(hv + alpha * dt * v);
                } else { // EPI == 3: final ht, f32 output
                    float hv = bs2f(hmat[off]);
                    outf[off] = hv + (dt * (1.0f / 6.0f)) * (S[off] + v);
                }
            }
        }
    }
}

// ---------- launch ----------
extern "C" void kernel_launch(void* const* d_in, const int* in_sizes, int n_in,
                              void* d_out, int out_size, void* d_ws, size_t ws_size,
                              hipStream_t stream) {
    // input mapping: dict order per spec; detect sorted-keys fallback from the size pattern.
    int IX = 0, IH0 = 1, IC0 = 2, ITS = 3, IWIH = 4, IWHH = 5, IBIH = 6, IBHH = 7,
        IW1 = 8, IB1 = 9, IW2 = 10, IB2 = 11;
    const bool sorted_ok = n_in >= 12 &&
        in_sizes[0] == 1024 && in_sizes[1] == 1024 && in_sizes[2] == 4096 &&
        in_sizes[3] == 4096 && in_sizes[4] == 4194304 && in_sizes[5] == 4194304 &&
        in_sizes[6] == 2097152 && in_sizes[7] == 8192 && in_sizes[8] == 1048576 &&
        in_sizes[9] == 1048576 && in_sizes[10] == 4194304 && in_sizes[11] == 2097152;
    if (sorted_ok) { // b1,b2,b_hh,b_ih,c0,h0,inputs,ts,w1,w2,w_hh,w_ih
        IB1 = 0; IB2 = 1; IBHH = 2; IBIH = 3; IC0 = 4; IH0 = 5;
        IX = 6; ITS = 7; IW1 = 8; IW2 = 9; IWHH = 10; IWIH = 11;
    }
    const float* x_f   = (const float*)d_in[IX];
    const float* h0_f  = (const float*)d_in[IH0];
    const float* c0_f  = (const float*)d_in[IC0];
    const float* ts_f  = (const float*)d_in[ITS];
    const float* wih_f = (const float*)d_in[IWIH];
    const float* whh_f = (const float*)d_in[IWHH];
    const float* bih_f = (const float*)d_in[IBIH];
    const float* bhh_f = (const float*)d_in[IBHH];
    const float* w1_f  = (const float*)d_in[IW1];
    const float* b1_f  = (const float*)d_in[IB1];
    const float* w2_f  = (const float*)d_in[IW2];
    const float* b2_f  = (const float*)d_in[IB2];

    constexpr size_t SZ_BIN  = (size_t)B_DIM * IN_DIM;       // 2M
    constexpr size_t SZ_BH   = (size_t)B_DIM * H_DIM;        // 4M
    constexpr size_t SZ_B4H  = (size_t)B_DIM * 4 * H_DIM;    // 16M
    constexpr size_t SZ_HH   = (size_t)H_DIM * H_DIM;        // 1M
    constexpr size_t SZ_WCAT = (size_t)4 * H_DIM * KCAT;     // 6M
    constexpr size_t SZ_XH   = (size_t)B_DIM * KCAT;         // 6M

    // workspace (~101 MB): f32 regions first, then bf16
    float* bsum = (float*)d_ws;                    // 4H
    float* dtv  = bsum + 4 * H_DIM;                // B
    float* S    = dtv + B_DIM;                     // [B,H] f32 (16 MB)
    float* c1f  = S + SZ_BH;                       // [B,H] f32 (16 MB)
    unsigned short* wcat  = (unsigned short*)(c1f + SZ_BH);  // [4H,KCAT] 12 MB
    unsigned short* w116  = wcat + SZ_WCAT;        // 2 MB
    unsigned short* w216  = w116 + SZ_HH;          // 2 MB
    unsigned short* xh    = w216 + SZ_HH;          // [B,KCAT] 12 MB
    unsigned short* h2    = xh + SZ_XH;            // [B,H] 8 MB
    unsigned short* gates = h2 + SZ_BH;            // [B,4H] 32 MB (dead after cellk2)
    unsigned short* ubuf  = gates;                 // alias: RK4 u (4M u16)
    unsigned short* ybuf  = gates + SZ_BH;         // alias: RK4 y (4M u16)

    float* out_ht = (float*)d_out;                 // [B,H] f32
    float* out_c  = out_ht + SZ_BH;                // [B,H] f32

    const int TB = 256;
    convs<<<(int)(SZ_BIN / 8 / TB), TB, 0, stream>>>(x_f,   xh,   (int)SZ_BIN, IN_DIM, KCAT, 0);
    convs<<<(int)(SZ_BH  / 8 / TB), TB, 0, stream>>>(h0_f,  xh,   (int)SZ_BH,  H_DIM,  KCAT, IN_DIM);
    convs<<<(int)(SZ_BIN / 8 / TB), TB, 0, stream>>>(wih_f, wcat, (int)SZ_BIN, IN_DIM, KCAT, 0);
    convs<<<(int)(SZ_BH  / 8 / TB), TB, 0, stream>>>(whh_f, wcat, (int)SZ_BH,  H_DIM,  KCAT, IN_DIM);
    convs<<<(int)(SZ_HH  / 8 / TB), TB, 0, stream>>>(w1_f,  w116, (int)SZ_HH,  H_DIM,  H_DIM, 0);
    convs<<<(int)(SZ_HH  / 8 / TB), TB, 0, stream>>>(w2_f,  w216, (int)SZ_HH,  H_DIM,  H_DIM, 0);
    prep_small<<<(4 * H_DIM) / TB, TB, 0, stream>>>(bih_f, bhh_f, ts_f, bsum, dtv, 4 * H_DIM, B_DIM);

    dim3 gBig(4 * H_DIM / BNt, B_DIM / BMt);   // (32,32)
    dim3 gSm(H_DIM / BNt, B_DIM / BMt);        // (8,32)
    const int cellBlocks = (int)(SZ_BH / 8 / TB);

    // cell 1: gates = [x|h0] @ [Wih|Whh]^T + (b_ih+b_hh); h1 -> xh (strided), c1 -> f32 ws
    gemm_bt<0><<<gBig, TB, 0, stream>>>(xh, wcat, B_DIM, 4 * H_DIM, KCAT, bsum,
                                        gates, nullptr, nullptr, nullptr, nullptr, nullptr, 0.f, 0.f, 0);
    cellk<<<cellBlocks, TB, 0, stream>>>(gates, c0_f, xh, KCAT, IN_DIM, c1f, B_DIM, H_DIM);
    // cell 2: gates = [x|h1] @ [Wih|Whh]^T + b; h2 -> bf16 ws, c2 -> d_out (f32)
    gemm_bt<0><<<gBig, TB, 0, stream>>>(xh, wcat, B_DIM, 4 * H_DIM, KCAT, bsum,
                                        gates, nullptr, nullptr, nullptr, nullptr, nullptr, 0.f, 0.f, 0);
    cellk<<<cellBlocks, TB, 0, stream>>>(gates, c1f, h2, H_DIM, 0, out_c, B_DIM, H_DIM);

    // RK4: f(y) = tanh(y@W1^T+b1)@W2^T + b2
    // stage 1
    gemm_bt<1><<<gSm, TB, 0, stream>>>(h2, w116, B_DIM, H_DIM, H_DIM, b1_f,
                                       ubuf, nullptr, nullptr, nullptr, nullptr, nullptr, 0.f, 0.f, 0);
    gemm_bt<2><<<gSm, TB, 0, stream>>>(ubuf, w216, B_DIM, H_DIM, H_DIM, b2_f,
                                       nullptr, nullptr, h2, dtv, S, ybuf, 0.5f, 1.0f, 1);
    // stage 2
    gemm_bt<1><<<gSm, TB, 0, stream>>>(ybuf, w116, B_DIM, H_DIM, H_DIM, b1_f,
                                       ubuf, nullptr, nullptr, nullptr, nullptr, nullptr, 0.f, 0.f, 0);
    gemm_bt<2><<<gSm, TB, 0, stream>>>(ubuf, w216, B_DIM, H_DIM, H_DIM, b2_f,
                                       nullptr, nullptr, h2, dtv, S, ybuf, 0.5f, 2.0f, 0);
    // stage 3
    gemm_bt<1><<<gSm, TB, 0, stream>>>(ybuf, w116, B_DIM, H_DIM, H_DIM, b1_f,
                                       ubuf, nullptr, nullptr, nullptr, nullptr, nullptr, 0.f, 0.f, 0);
    gemm_bt<2><<<gSm, TB, 0, stream>>>(ubuf, w216, B_DIM, H_DIM, H_DIM, b2_f,
                                       nullptr, nullptr, h2, dtv, S, ybuf, 1.0f, 2.0f, 0);
    // stage 4 (final): ht -> d_out (f32)
    gemm_bt<1><<<gSm, TB, 0, stream>>>(ybuf, w116, B_DIM, H_DIM, H_DIM, b1_f,
                                       ubuf, nullptr, nullptr, nullptr, nullptr, nullptr, 0.f, 0.f, 0);
    gemm_bt<3><<<gSm, TB, 0, stream>>>(ubuf, w216, B_DIM, H_DIM, H_DIM, b2_f,
                                       nullptr, out_ht, h2, dtv, S, nullptr, 0.f, 0.f, 0);
}

// Round 6
// 462.206 us; speedup vs baseline: 1.3102x; 1.3102x over previous
//
#include <hip/hip_runtime.h>

// ---------- types ----------
typedef short short8 __attribute__((ext_vector_type(8)));     // 8 bf16 bit-patterns (4 VGPRs) - MFMA A/B frag
typedef float f32x4 __attribute__((ext_vector_type(4)));      // MFMA C/D frag
typedef unsigned short u16x8 __attribute__((ext_vector_type(8)));

#define B_DIM 4096
#define IN_DIM 512
#define H_DIM 1024
#define KCAT 1536   // IN_DIM + H_DIM

__device__ __forceinline__ float bs2f(unsigned short s) {
    return __uint_as_float(((unsigned int)s) << 16);
}
__device__ __forceinline__ unsigned short f2bs(float f) {
    unsigned int u = __float_as_uint(f);
    u += 0x7fff + ((u >> 16) & 1);   // RNE
    return (unsigned short)(u >> 16);
}
__device__ __forceinline__ float sigm(float x) { return 1.0f / (1.0f + __expf(-x)); }
__device__ __forceinline__ float ftanh(float x) { return 1.0f - 2.0f / (__expf(2.0f * x) + 1.0f); }

// ---------- fused f32 -> bf16 pack of all 6 operand segments ----------
// group g = 8 elements. Segment bounds in groups (compile-time):
#define S0 262144    // x    [4096,512]  -> xh   (ld 1536, off 0)
#define S1 786432    // h0   [4096,1024] -> xh   (ld 1536, off 512)
#define S2 1048576   // wih  [4096,512]  -> wcat (ld 1536, off 0)
#define S3 1572864   // whh  [4096,1024] -> wcat (ld 1536, off 512)
#define S4 1703936   // w1   [1024,1024] -> w116
#define S5 1835008   // w2   [1024,1024] -> w216
__device__ __forceinline__ void packseg(const float* __restrict__ in, long gl,
                                        int width, int ld, int off,
                                        unsigned short* __restrict__ out) {
    long i = gl * 8;
    int r = (int)(i / width);
    int c = (int)(i % width);     // width % 8 == 0 -> all 8 in-row
    float4 a = *(const float4*)(in + i);
    float4 b = *(const float4*)(in + i + 4);
    u16x8 o;
    o[0] = f2bs(a.x); o[1] = f2bs(a.y); o[2] = f2bs(a.z); o[3] = f2bs(a.w);
    o[4] = f2bs(b.x); o[5] = f2bs(b.y); o[6] = f2bs(b.z); o[7] = f2bs(b.w);
    *(u16x8*)(out + (size_t)r * ld + off + c) = o;
}
__global__ __launch_bounds__(256) void pack_all(const float* __restrict__ x,
                                                const float* __restrict__ h0,
                                                const float* __restrict__ wih,
                                                const float* __restrict__ whh,
                                                const float* __restrict__ w1,
                                                const float* __restrict__ w2,
                                                unsigned short* __restrict__ xh,
                                                unsigned short* __restrict__ wcat,
                                                unsigned short* __restrict__ w116,
                                                unsigned short* __restrict__ w216) {
    long g = (long)blockIdx.x * 256 + threadIdx.x;
    if (g < S0)       packseg(x,   g,      IN_DIM, KCAT, 0,      xh);
    else if (g < S1)  packseg(h0,  g - S0, H_DIM,  KCAT, IN_DIM, xh);
    else if (g < S2)  packseg(wih, g - S1, IN_DIM, KCAT, 0,      wcat);
    else if (g < S3)  packseg(whh, g - S2, H_DIM,  KCAT, IN_DIM, wcat);
    else if (g < S4)  packseg(w1,  g - S3, H_DIM,  H_DIM, 0,     w116);
    else if (g < S5)  packseg(w2,  g - S4, H_DIM,  H_DIM, 0,     w216);
}

// ---------- bias sum + dt ----------
__global__ __launch_bounds__(256) void prep_small(const float* __restrict__ bih,
                                                  const float* __restrict__ bhh,
                                                  const float* __restrict__ ts,
                                                  float* __restrict__ bsum,
                                                  float* __restrict__ dtv,
                                                  int n4h, int nb) {
    int i = blockIdx.x * blockDim.x + threadIdx.x;
    if (i < n4h) bsum[i] = bih[i] + bhh[i];
    if (i < nb)  dtv[i] = ts[2 * i + 1] - ts[2 * i];
}

// ---------- LSTM cell elementwise: c path in f32, h out bf16 (strided), c out f32 ----------
__global__ __launch_bounds__(256) void cellk(const unsigned short* __restrict__ gates, // [B,4H] bf16
                                             const float* __restrict__ c_in,           // [B,H] f32
                                             unsigned short* __restrict__ h_out,       // strided bf16
                                             int h_ld, int h_off,
                                             float* __restrict__ c_out,                // [B,H] f32
                                             int Bn, int Hn) {
    int tid = blockIdx.x * blockDim.x + threadIdx.x;
    long e = (long)tid * 8;
    if (e >= (long)Bn * Hn) return;
    int b = (int)(e / Hn);
    int j = (int)(e % Hn);
    const unsigned short* g0 = gates + (size_t)b * 4 * Hn + j;
    u16x8 gi = *(const u16x8*)(g0);
    u16x8 gf = *(const u16x8*)(g0 + Hn);
    u16x8 gg = *(const u16x8*)(g0 + 2 * Hn);
    u16x8 go = *(const u16x8*)(g0 + 3 * Hn);
    float4 ca = *(const float4*)(c_in + e);
    float4 cb = *(const float4*)(c_in + e + 4);
    float cin[8] = {ca.x, ca.y, ca.z, ca.w, cb.x, cb.y, cb.z, cb.w};
    u16x8 ho;
    float co[8];
    #pragma unroll
    for (int q = 0; q < 8; ++q) {
        float iv = sigm(bs2f(gi[q]));
        float fv = sigm(bs2f(gf[q]));
        float gv = ftanh(bs2f(gg[q]));
        float ov = sigm(bs2f(go[q]));
        float cn = fv * cin[q] + iv * gv;
        float hn = ov * ftanh(cn);
        ho[q] = f2bs(hn);
        co[q] = cn;
    }
    *(u16x8*)(h_out + (size_t)b * h_ld + h_off + j) = ho;
    *(float4*)(c_out + e) = make_float4(co[0], co[1], co[2], co[3]);
    *(float4*)(c_out + e + 4) = make_float4(co[4], co[5], co[6], co[7]);
}

// ---------- GEMM: C[m,n] = sum_k A[m,k]*W[n,k]  (A:[M,K], W:[N,K], both bf16) ----------
// 2-phase double-buffered pipeline (T3 minimum-2-phase): stage(next) -> ds_read(cur)+MFMA
// -> one __syncthreads (implicit vmcnt(0) drain makes dbuf race-free).
// Tiles: gates 128x128 (4 waves 2x2, wave 64x64); RK4 64x128 (wave 32x64, 512 blocks).
// EPI: 0 = bf16(acc+bias) -> outb
//      1 = bf16(tanh(acc+bias)) -> outb
//      2 = k=acc+bias; S=(first?0:S)+cw*k; ynext=bf16(h+alpha*dt*k)
//      3 = k=acc+bias; outf=f32(h + dt/6*(S+k))
#define BKt 32

template <int EPI, int BM, int BN>
__global__ __launch_bounds__(256) void gemm2(
    const unsigned short* __restrict__ A,
    const unsigned short* __restrict__ W,
    const int M, const int N, const int K,
    const float* __restrict__ bias,
    unsigned short* __restrict__ outb,
    float* __restrict__ outf,
    const unsigned short* __restrict__ hmat,
    const float* __restrict__ dtv,
    float* __restrict__ S,
    unsigned short* __restrict__ ynext,
    const float alpha, const float cw, const int first) {
    constexpr int WM = BM / 2;        // rows per wave (2x2 wave grid)
    constexpr int WN = BN / 2;        // cols per wave
    constexpr int MR = WM / 16;
    constexpr int NR = WN / 16;
    constexpr int ALOADS = BM * BKt / 8 / 256;   // 16B loads per thread for A
    constexpr int BLOADS = BN * BKt / 8 / 256;

    __shared__ unsigned short lA[2][BM * BKt];
    __shared__ unsigned short lB[2][BN * BKt];
    const int t = threadIdx.x;
    const int lane = t & 63;
    const int wave = t >> 6;
    const int wm = (wave >> 1) * WM;
    const int wn = (wave & 1) * WN;
    const int fr = lane & 15;
    const int kb = lane >> 4;
    const int tile_m = blockIdx.y * BM;
    const int tile_n = blockIdx.x * BN;

    f32x4 acc[MR][NR];
    #pragma unroll
    for (int i = 0; i < MR; ++i)
        #pragma unroll
        for (int j = 0; j < NR; ++j)
            acc[i][j] = (f32x4){0.f, 0.f, 0.f, 0.f};

    const unsigned short* aptr = A + (size_t)tile_m * K;
    const unsigned short* wptr = W + (size_t)tile_n * K;

    auto stage = [&](int buf, int k0) {
        #pragma unroll
        for (int j = 0; j < ALOADS; ++j) {
            int idx = j * 256 + t;
            int row = idx >> 2;
            int col = (idx & 3) * 8;
            __builtin_amdgcn_global_load_lds(
                (__attribute__((address_space(1))) void*)(aptr + (size_t)row * K + k0 + col),
                (__attribute__((address_space(3))) void*)(&lA[buf][idx * 8]), 16, 0, 0);
        }
        #pragma unroll
        for (int j = 0; j < BLOADS; ++j) {
            int idx = j * 256 + t;
            int row = idx >> 2;
            int col = (idx & 3) * 8;
            __builtin_amdgcn_global_load_lds(
                (__attribute__((address_space(1))) void*)(wptr + (size_t)row * K + k0 + col),
                (__attribute__((address_space(3))) void*)(&lB[buf][idx * 8]), 16, 0, 0);
        }
    };

    stage(0, 0);
    __syncthreads();                       // drain vmcnt: buf0 ready
    int cur = 0;
    const int NT = K / BKt;
    for (int kt = 0; kt < NT; ++kt) {
        if (kt + 1 < NT) stage(cur ^ 1, (kt + 1) * BKt);   // issue next tile (overlaps compute)
        short8 af[MR], bfr[NR];
        #pragma unroll
        for (int i = 0; i < MR; ++i)
            af[i] = *(const short8*)&lA[cur][(wm + i * 16 + fr) * BKt + kb * 8];
        #pragma unroll
        for (int j = 0; j < NR; ++j)
            bfr[j] = *(const short8*)&lB[cur][(wn + j * 16 + fr) * BKt + kb * 8];
        #pragma unroll
        for (int i = 0; i < MR; ++i)
            #pragma unroll
            for (int j = 0; j < NR; ++j)
                acc[i][j] = __builtin_amdgcn_mfma_f32_16x16x32_bf16(af[i], bfr[j], acc[i][j], 0, 0, 0);
        __syncthreads();                   // drains vmcnt(0): next buf staged + all reads done
        cur ^= 1;
    }

    // epilogue: D element (col = lane&15 -> n, row = (lane>>4)*4+r -> m)
    #pragma unroll
    for (int i = 0; i < MR; ++i) {
        #pragma unroll
        for (int r = 0; r < 4; ++r) {
            const int m = tile_m + wm + i * 16 + kb * 4 + r;
            float dt = 0.f;
            if (EPI >= 2) dt = dtv[m];
            #pragma unroll
            for (int j = 0; j < NR; ++j) {
                const int n = tile_n + wn + j * 16 + fr;
                const size_t off = (size_t)m * N + n;
                float v = acc[i][j][r];
                if (bias) v += bias[n];
                if (EPI == 0) {
                    outb[off] = f2bs(v);
                } else if (EPI == 1) {
                    outb[off] = f2bs(ftanh(v));
                } else if (EPI == 2) {
                    float hv = bs2f(hmat[off]);
                    float s = first ? 0.f : S[off];
                    S[off] = s + cw * v;
                    ynext[off] = f2bs(hv + alpha * dt * v);
                } else { // EPI == 3: final ht, f32 output
                    float hv = bs2f(hmat[off]);
                    outf[off] = hv + (dt * (1.0f / 6.0f)) * (S[off] + v);
                }
            }
        }
    }
}

// ---------- launch ----------
extern "C" void kernel_launch(void* const* d_in, const int* in_sizes, int n_in,
                              void* d_out, int out_size, void* d_ws, size_t ws_size,
                              hipStream_t stream) {
    int IX = 0, IH0 = 1, IC0 = 2, ITS = 3, IWIH = 4, IWHH = 5, IBIH = 6, IBHH = 7,
        IW1 = 8, IB1 = 9, IW2 = 10, IB2 = 11;
    const bool sorted_ok = n_in >= 12 &&
        in_sizes[0] == 1024 && in_sizes[1] == 1024 && in_sizes[2] == 4096 &&
        in_sizes[3] == 4096 && in_sizes[4] == 4194304 && in_sizes[5] == 4194304 &&
        in_sizes[6] == 2097152 && in_sizes[7] == 8192 && in_sizes[8] == 1048576 &&
        in_sizes[9] == 1048576 && in_sizes[10] == 4194304 && in_sizes[11] == 2097152;
    if (sorted_ok) { // b1,b2,b_hh,b_ih,c0,h0,inputs,ts,w1,w2,w_hh,w_ih
        IB1 = 0; IB2 = 1; IBHH = 2; IBIH = 3; IC0 = 4; IH0 = 5;
        IX = 6; ITS = 7; IW1 = 8; IW2 = 9; IWHH = 10; IWIH = 11;
    }
    const float* x_f   = (const float*)d_in[IX];
    const float* h0_f  = (const float*)d_in[IH0];
    const float* c0_f  = (const float*)d_in[IC0];
    const float* ts_f  = (const float*)d_in[ITS];
    const float* wih_f = (const float*)d_in[IWIH];
    const float* whh_f = (const float*)d_in[IWHH];
    const float* bih_f = (const float*)d_in[IBIH];
    const float* bhh_f = (const float*)d_in[IBHH];
    const float* w1_f  = (const float*)d_in[IW1];
    const float* b1_f  = (const float*)d_in[IB1];
    const float* w2_f  = (const float*)d_in[IW2];
    const float* b2_f  = (const float*)d_in[IB2];

    constexpr size_t SZ_BH   = (size_t)B_DIM * H_DIM;        // 4M
    constexpr size_t SZ_B4H  = (size_t)B_DIM * 4 * H_DIM;    // 16M
    constexpr size_t SZ_HH   = (size_t)H_DIM * H_DIM;        // 1M
    constexpr size_t SZ_WCAT = (size_t)4 * H_DIM * KCAT;     // 6M
    constexpr size_t SZ_XH   = (size_t)B_DIM * KCAT;         // 6M

    // workspace (~101 MB): f32 regions first, then bf16 (layout identical to passing round)
    float* bsum = (float*)d_ws;                    // 4H
    float* dtv  = bsum + 4 * H_DIM;                // B
    float* S    = dtv + B_DIM;                     // [B,H] f32 (16 MB)
    float* c1f  = S + SZ_BH;                       // [B,H] f32 (16 MB)
    unsigned short* wcat  = (unsigned short*)(c1f + SZ_BH);  // [4H,KCAT]
    unsigned short* w116  = wcat + SZ_WCAT;
    unsigned short* w216  = w116 + SZ_HH;
    unsigned short* xh    = w216 + SZ_HH;          // [B,KCAT]
    unsigned short* h2    = xh + SZ_XH;            // [B,H]
    unsigned short* gates = h2 + SZ_BH;            // [B,4H] (dead after cellk2)
    unsigned short* ubuf  = gates;                 // alias: RK4 u
    unsigned short* ybuf  = gates + SZ_BH;         // alias: RK4 y

    float* out_ht = (float*)d_out;                 // [B,H] f32
    float* out_c  = out_ht + SZ_BH;                // [B,H] f32

    const int TB = 256;
    pack_all<<<S5 / TB, TB, 0, stream>>>(x_f, h0_f, wih_f, whh_f, w1_f, w2_f,
                                         xh, wcat, w116, w216);
    prep_small<<<(4 * H_DIM) / TB, TB, 0, stream>>>(bih_f, bhh_f, ts_f, bsum, dtv, 4 * H_DIM, B_DIM);

    dim3 gBig(4 * H_DIM / 128, B_DIM / 128);   // (32,32) = 1024 blocks
    dim3 gSm(H_DIM / 128, B_DIM / 64);         // (8,64)  = 512 blocks
    const int cellBlocks = (int)(SZ_BH / 8 / TB);

    // cell 1: gates = [x|h0] @ [Wih|Whh]^T + (b_ih+b_hh); h1 -> xh (strided), c1 -> f32 ws
    gemm2<0, 128, 128><<<gBig, TB, 0, stream>>>(xh, wcat, B_DIM, 4 * H_DIM, KCAT, bsum,
                                                gates, nullptr, nullptr, nullptr, nullptr, nullptr, 0.f, 0.f, 0);
    cellk<<<cellBlocks, TB, 0, stream>>>(gates, c0_f, xh, KCAT, IN_DIM, c1f, B_DIM, H_DIM);
    // cell 2: gates = [x|h1] @ [Wih|Whh]^T + b; h2 -> bf16 ws, c2 -> d_out (f32)
    gemm2<0, 128, 128><<<gBig, TB, 0, stream>>>(xh, wcat, B_DIM, 4 * H_DIM, KCAT, bsum,
                                                gates, nullptr, nullptr, nullptr, nullptr, nullptr, 0.f, 0.f, 0);
    cellk<<<cellBlocks, TB, 0, stream>>>(gates, c1f, h2, H_DIM, 0, out_c, B_DIM, H_DIM);

    // RK4: f(y) = tanh(y@W1^T+b1)@W2^T + b2
    // stage 1
    gemm2<1, 64, 128><<<gSm, TB, 0, stream>>>(h2, w116, B_DIM, H_DIM, H_DIM, b1_f,
                                              ubuf, nullptr, nullptr, nullptr, nullptr, nullptr, 0.f, 0.f, 0);
    gemm2<2, 64, 128><<<gSm, TB, 0, stream>>>(ubuf, w216, B_DIM, H_DIM, H_DIM, b2_f,
                                              nullptr, nullptr, h2, dtv, S, ybuf, 0.5f, 1.0f, 1);
    // stage 2
    gemm2<1, 64, 128><<<gSm, TB, 0, stream>>>(ybuf, w116, B_DIM, H_DIM, H_DIM, b1_f,
                                              ubuf, nullptr, nullptr, nullptr, nullptr, nullptr, 0.f, 0.f, 0);
    gemm2<2, 64, 128><<<gSm, TB, 0, stream>>>(ubuf, w216, B_DIM, H_DIM, H_DIM, b2_f,
                                              nullptr, nullptr, h2, dtv, S, ybuf, 0.5f, 2.0f, 0);
    // stage 3
    gemm2<1, 64, 128><<<gSm, TB, 0, stream>>>(ybuf, w116, B_DIM, H_DIM, H_DIM, b1_f,
                                              ubuf, nullptr, nullptr, nullptr, nullptr, nullptr, 0.f, 0.f, 0);
    gemm2<2, 64, 128><<<gSm, TB, 0, stream>>>(ubuf, w216, B_DIM, H_DIM, H_DIM, b2_f,
                                              nullptr, nullptr, h2, dtv, S, ybuf, 1.0f, 2.0f, 0);
    // stage 4 (final): ht -> d_out (f32)
    gemm2<1, 64, 128><<<gSm, TB, 0, stream>>>(ybuf, w116, B_DIM, H_DIM, H_DIM, b1_f,
                                              ubuf, nullptr, nullptr, nullptr, nullptr, nullptr, 0.f, 0.f, 0);
    gemm2<3, 64, 128><<<gSm, TB, 0, stream>>>(ubuf, w216, B_DIM, H_DIM, H_DIM, b2_f,
                                              nullptr, out_ht, h2, dtv, S, nullptr, 0.f, 0.f, 0);
}

// Round 7
// 453.760 us; speedup vs baseline: 1.3346x; 1.0186x over previous
//
#include <hip/hip_runtime.h>

// ---------- types ----------
typedef short short8 __attribute__((ext_vector_type(8)));     // 8 bf16 bit-patterns (4 VGPRs) - MFMA A/B frag
typedef float f32x4 __attribute__((ext_vector_type(4)));      // MFMA C/D frag
typedef unsigned short u16x8 __attribute__((ext_vector_type(8)));

#define B_DIM 4096
#define IN_DIM 512
#define H_DIM 1024
#define KCAT 1536   // IN_DIM + H_DIM

__device__ __forceinline__ float bs2f(unsigned short s) {
    return __uint_as_float(((unsigned int)s) << 16);
}
__device__ __forceinline__ unsigned short f2bs(float f) {
    unsigned int u = __float_as_uint(f);
    u += 0x7fff + ((u >> 16) & 1);   // RNE
    return (unsigned short)(u >> 16);
}
__device__ __forceinline__ float sigm(float x) { return 1.0f / (1.0f + __expf(-x)); }
__device__ __forceinline__ float ftanh(float x) { return 1.0f - 2.0f / (__expf(2.0f * x) + 1.0f); }

// ---------- fused f32 -> bf16 pack of all 6 operand segments ----------
#define S0 262144    // x    [4096,512]  -> xh   (ld 1536, off 0)
#define S1 786432    // h0   [4096,1024] -> xh   (ld 1536, off 512)
#define S2 1048576   // wih  [4096,512]  -> wcat (ld 1536, off 0)
#define S3 1572864   // whh  [4096,1024] -> wcat (ld 1536, off 512)
#define S4 1703936   // w1   [1024,1024] -> w116
#define S5 1835008   // w2   [1024,1024] -> w216
__device__ __forceinline__ void packseg(const float* __restrict__ in, long gl,
                                        int width, int ld, int off,
                                        unsigned short* __restrict__ out) {
    long i = gl * 8;
    int r = (int)(i / width);
    int c = (int)(i % width);     // width % 8 == 0 -> all 8 in-row
    float4 a = *(const float4*)(in + i);
    float4 b = *(const float4*)(in + i + 4);
    u16x8 o;
    o[0] = f2bs(a.x); o[1] = f2bs(a.y); o[2] = f2bs(a.z); o[3] = f2bs(a.w);
    o[4] = f2bs(b.x); o[5] = f2bs(b.y); o[6] = f2bs(b.z); o[7] = f2bs(b.w);
    *(u16x8*)(out + (size_t)r * ld + off + c) = o;
}
__global__ __launch_bounds__(256) void pack_all(const float* __restrict__ x,
                                                const float* __restrict__ h0,
                                                const float* __restrict__ wih,
                                                const float* __restrict__ whh,
                                                const float* __restrict__ w1,
                                                const float* __restrict__ w2,
                                                unsigned short* __restrict__ xh,
                                                unsigned short* __restrict__ wcat,
                                                unsigned short* __restrict__ w116,
                                                unsigned short* __restrict__ w216) {
    long g = (long)blockIdx.x * 256 + threadIdx.x;
    if (g < S0)       packseg(x,   g,      IN_DIM, KCAT, 0,      xh);
    else if (g < S1)  packseg(h0,  g - S0, H_DIM,  KCAT, IN_DIM, xh);
    else if (g < S2)  packseg(wih, g - S1, IN_DIM, KCAT, 0,      wcat);
    else if (g < S3)  packseg(whh, g - S2, H_DIM,  KCAT, IN_DIM, wcat);
    else if (g < S4)  packseg(w1,  g - S3, H_DIM,  H_DIM, 0,     w116);
    else if (g < S5)  packseg(w2,  g - S4, H_DIM,  H_DIM, 0,     w216);
}

// ---------- bias sum + dt ----------
__global__ __launch_bounds__(256) void prep_small(const float* __restrict__ bih,
                                                  const float* __restrict__ bhh,
                                                  const float* __restrict__ ts,
                                                  float* __restrict__ bsum,
                                                  float* __restrict__ dtv,
                                                  int n4h, int nb) {
    int i = blockIdx.x * blockDim.x + threadIdx.x;
    if (i < n4h) bsum[i] = bih[i] + bhh[i];
    if (i < nb)  dtv[i] = ts[2 * i + 1] - ts[2 * i];
}

// ---------- LSTM cell elementwise: c path in f32, h out bf16 (strided), c out f32 ----------
__global__ __launch_bounds__(256) void cellk(const unsigned short* __restrict__ gates, // [B,4H] bf16
                                             const float* __restrict__ c_in,           // [B,H] f32
                                             unsigned short* __restrict__ h_out,       // strided bf16
                                             int h_ld, int h_off,
                                             float* __restrict__ c_out,                // [B,H] f32
                                             int Bn, int Hn) {
    int tid = blockIdx.x * blockDim.x + threadIdx.x;
    long e = (long)tid * 8;
    if (e >= (long)Bn * Hn) return;
    int b = (int)(e / Hn);
    int j = (int)(e % Hn);
    const unsigned short* g0 = gates + (size_t)b * 4 * Hn + j;
    u16x8 gi = *(const u16x8*)(g0);
    u16x8 gf = *(const u16x8*)(g0 + Hn);
    u16x8 gg = *(const u16x8*)(g0 + 2 * Hn);
    u16x8 go = *(const u16x8*)(g0 + 3 * Hn);
    float4 ca = *(const float4*)(c_in + e);
    float4 cb = *(const float4*)(c_in + e + 4);
    float cin[8] = {ca.x, ca.y, ca.z, ca.w, cb.x, cb.y, cb.z, cb.w};
    u16x8 ho;
    float co[8];
    #pragma unroll
    for (int q = 0; q < 8; ++q) {
        float iv = sigm(bs2f(gi[q]));
        float fv = sigm(bs2f(gf[q]));
        float gv = ftanh(bs2f(gg[q]));
        float ov = sigm(bs2f(go[q]));
        float cn = fv * cin[q] + iv * gv;
        float hn = ov * ftanh(cn);
        ho[q] = f2bs(hn);
        co[q] = cn;
    }
    *(u16x8*)(h_out + (size_t)b * h_ld + h_off + j) = ho;
    *(float4*)(c_out + e) = make_float4(co[0], co[1], co[2], co[3]);
    *(float4*)(c_out + e + 4) = make_float4(co[4], co[5], co[6], co[7]);
}

// ---------- GEMM: C[m,n] = sum_k A[m,k]*W[n,k]  (A:[M,K], W:[N,K], both bf16) ----------
// Counted-vmcnt 2-deep prefetch (T3/T4): stage(kt+2) issued at end of iter kt; iter kt
// begins with s_waitcnt vmcnt(LOADS) (waits ONLY the oldest stage) + raw s_barrier.
// No vmcnt(0) drain in the main loop -> loads have ~2 iterations of slack.
// Race-safety: each wave waits its own vmcnt BEFORE the barrier, so post-barrier the
// buffer is collectively complete; uniform control flow keeps barriers aligned.
// EPI: 0 = bf16(acc+bias) -> outb
//      1 = bf16(tanh(acc+bias)) -> outb
//      2 = k=acc+bias; S=(first?0:S)+cw*k; ynext=bf16(h+alpha*dt*k)
//      3 = k=acc+bias; outf=f32(h + dt/6*(S+k))
#define BKt 32

template <int EPI, int BM, int BN>
__global__ __launch_bounds__(256) void gemm2(
    const unsigned short* __restrict__ A,
    const unsigned short* __restrict__ W,
    const int M, const int N, const int K,
    const float* __restrict__ bias,
    unsigned short* __restrict__ outb,
    float* __restrict__ outf,
    const unsigned short* __restrict__ hmat,
    const float* __restrict__ dtv,
    float* __restrict__ S,
    unsigned short* __restrict__ ynext,
    const float alpha, const float cw, const int first) {
    constexpr int WM = BM / 2;        // rows per wave (2x2 wave grid)
    constexpr int WN = BN / 2;        // cols per wave
    constexpr int MR = WM / 16;
    constexpr int NR = WN / 16;
    constexpr int ALOADS = BM * BKt / 8 / 256;   // 16B loads per thread for A
    constexpr int BLOADS = BN * BKt / 8 / 256;
    constexpr int LIF = ALOADS + BLOADS;         // loads in flight per stage

    __shared__ unsigned short lA[2][BM * BKt];
    __shared__ unsigned short lB[2][BN * BKt];
    const int t = threadIdx.x;
    const int lane = t & 63;
    const int wave = t >> 6;
    const int wm = (wave >> 1) * WM;
    const int wn = (wave & 1) * WN;
    const int fr = lane & 15;
    const int kb = lane >> 4;

    // XCD-aware bijective swizzle (grids are multiples of 8)
    const int nwg = gridDim.x * gridDim.y;
    const int linear = blockIdx.y * gridDim.x + blockIdx.x;
    const int cpx = nwg >> 3;
    const int swz = (linear & 7) * cpx + (linear >> 3);
    const int bx = swz % gridDim.x;
    const int by = swz / gridDim.x;
    const int tile_m = by * BM;
    const int tile_n = bx * BN;

    f32x4 acc[MR][NR];
    #pragma unroll
    for (int i = 0; i < MR; ++i)
        #pragma unroll
        for (int j = 0; j < NR; ++j)
            acc[i][j] = (f32x4){0.f, 0.f, 0.f, 0.f};

    const unsigned short* aptr = A + (size_t)tile_m * K;
    const unsigned short* wptr = W + (size_t)tile_n * K;

    auto stage = [&](int buf, int k0) {
        #pragma unroll
        for (int j = 0; j < ALOADS; ++j) {
            int idx = j * 256 + t;
            int row = idx >> 2;
            int col = (idx & 3) * 8;
            __builtin_amdgcn_global_load_lds(
                (__attribute__((address_space(1))) void*)(aptr + (size_t)row * K + k0 + col),
                (__attribute__((address_space(3))) void*)(&lA[buf][idx * 8]), 16, 0, 0);
        }
        #pragma unroll
        for (int j = 0; j < BLOADS; ++j) {
            int idx = j * 256 + t;
            int row = idx >> 2;
            int col = (idx & 3) * 8;
            __builtin_amdgcn_global_load_lds(
                (__attribute__((address_space(1))) void*)(wptr + (size_t)row * K + k0 + col),
                (__attribute__((address_space(3))) void*)(&lB[buf][idx * 8]), 16, 0, 0);
        }
    };

    const int NT = K / BKt;
    stage(0, 0);
    if (NT > 1) stage(1, BKt);
    int cur = 0;
    for (int kt = 0; kt < NT; ++kt) {
        // wait own oldest stage (tile kt) landed; newer stage (kt+1) stays in flight
        if (kt + 1 < NT) {
            if constexpr (LIF == 4) asm volatile("s_waitcnt vmcnt(4)" ::: "memory");
            else if constexpr (LIF == 3) asm volatile("s_waitcnt vmcnt(3)" ::: "memory");
            else asm volatile("s_waitcnt vmcnt(0)" ::: "memory");
        } else {
            asm volatile("s_waitcnt vmcnt(0)" ::: "memory");
        }
        __builtin_amdgcn_s_barrier();      // all waves' stage(kt) complete -> buf cur readable
        short8 af[MR], bfr[NR];
        #pragma unroll
        for (int i = 0; i < MR; ++i)
            af[i] = *(const short8*)&lA[cur][(wm + i * 16 + fr) * BKt + kb * 8];
        #pragma unroll
        for (int j = 0; j < NR; ++j)
            bfr[j] = *(const short8*)&lB[cur][(wn + j * 16 + fr) * BKt + kb * 8];
        #pragma unroll
        for (int i = 0; i < MR; ++i)
            #pragma unroll
            for (int j = 0; j < NR; ++j)
                acc[i][j] = __builtin_amdgcn_mfma_f32_16x16x32_bf16(af[i], bfr[j], acc[i][j], 0, 0, 0);
        asm volatile("" ::: "memory");     // pin ds_reads before the barrier
        __builtin_amdgcn_s_barrier();      // all waves done reading buf cur
        if (kt + 2 < NT) stage(cur, (kt + 2) * BKt);   // overwrite just-freed buffer
        cur ^= 1;
    }

    // epilogue: D element (col = lane&15 -> n, row = (lane>>4)*4+r -> m)
    #pragma unroll
    for (int i = 0; i < MR; ++i) {
        #pragma unroll
        for (int r = 0; r < 4; ++r) {
            const int m = tile_m + wm + i * 16 + kb * 4 + r;
            float dt = 0.f;
            if (EPI >= 2) dt = dtv[m];
            #pragma unroll
            for (int j = 0; j < NR; ++j) {
                const int n = tile_n + wn + j * 16 + fr;
                const size_t off = (size_t)m * N + n;
                float v = acc[i][j][r];
                if (bias) v += bias[n];
                if (EPI == 0) {
                    outb[off] = f2bs(v);
                } else if (EPI == 1) {
                    outb[off] = f2bs(ftanh(v));
                } else if (EPI == 2) {
                    float hv = bs2f(hmat[off]);
                    float s = first ? 0.f : S[off];
                    S[off] = s + cw * v;
                    ynext[off] = f2bs(hv + alpha * dt * v);
                } else { // EPI == 3: final ht, f32 output
                    float hv = bs2f(hmat[off]);
                    outf[off] = hv + (dt * (1.0f / 6.0f)) * (S[off] + v);
                }
            }
        }
    }
}

// ---------- launch ----------
extern "C" void kernel_launch(void* const* d_in, const int* in_sizes, int n_in,
                              void* d_out, int out_size, void* d_ws, size_t ws_size,
                              hipStream_t stream) {
    int IX = 0, IH0 = 1, IC0 = 2, ITS = 3, IWIH = 4, IWHH = 5, IBIH = 6, IBHH = 7,
        IW1 = 8, IB1 = 9, IW2 = 10, IB2 = 11;
    const bool sorted_ok = n_in >= 12 &&
        in_sizes[0] == 1024 && in_sizes[1] == 1024 && in_sizes[2] == 4096 &&
        in_sizes[3] == 4096 && in_sizes[4] == 4194304 && in_sizes[5] == 4194304 &&
        in_sizes[6] == 2097152 && in_sizes[7] == 8192 && in_sizes[8] == 1048576 &&
        in_sizes[9] == 1048576 && in_sizes[10] == 4194304 && in_sizes[11] == 2097152;
    if (sorted_ok) { // b1,b2,b_hh,b_ih,c0,h0,inputs,ts,w1,w2,w_hh,w_ih
        IB1 = 0; IB2 = 1; IBHH = 2; IBIH = 3; IC0 = 4; IH0 = 5;
        IX = 6; ITS = 7; IW1 = 8; IW2 = 9; IWHH = 10; IWIH = 11;
    }
    const float* x_f   = (const float*)d_in[IX];
    const float* h0_f  = (const float*)d_in[IH0];
    const float* c0_f  = (const float*)d_in[IC0];
    const float* ts_f  = (const float*)d_in[ITS];
    const float* wih_f = (const float*)d_in[IWIH];
    const float* whh_f = (const float*)d_in[IWHH];
    const float* bih_f = (const float*)d_in[IBIH];
    const float* bhh_f = (const float*)d_in[IBHH];
    const float* w1_f  = (const float*)d_in[IW1];
    const float* b1_f  = (const float*)d_in[IB1];
    const float* w2_f  = (const float*)d_in[IW2];
    const float* b2_f  = (const float*)d_in[IB2];

    constexpr size_t SZ_BH   = (size_t)B_DIM * H_DIM;        // 4M
    constexpr size_t SZ_B4H  = (size_t)B_DIM * 4 * H_DIM;    // 16M
    constexpr size_t SZ_HH   = (size_t)H_DIM * H_DIM;        // 1M
    constexpr size_t SZ_WCAT = (size_t)4 * H_DIM * KCAT;     // 6M
    constexpr size_t SZ_XH   = (size_t)B_DIM * KCAT;         // 6M

    // workspace (~101 MB): f32 regions first, then bf16 (layout identical to passing round)
    float* bsum = (float*)d_ws;                    // 4H
    float* dtv  = bsum + 4 * H_DIM;                // B
    float* S    = dtv + B_DIM;                     // [B,H] f32 (16 MB)
    float* c1f  = S + SZ_BH;                       // [B,H] f32 (16 MB)
    unsigned short* wcat  = (unsigned short*)(c1f + SZ_BH);  // [4H,KCAT]
    unsigned short* w116  = wcat + SZ_WCAT;
    unsigned short* w216  = w116 + SZ_HH;
    unsigned short* xh    = w216 + SZ_HH;          // [B,KCAT]
    unsigned short* h2    = xh + SZ_XH;            // [B,H]
    unsigned short* gates = h2 + SZ_BH;            // [B,4H] (dead after cellk2)
    unsigned short* ubuf  = gates;                 // alias: RK4 u
    unsigned short* ybuf  = gates + SZ_BH;         // alias: RK4 y

    float* out_ht = (float*)d_out;                 // [B,H] f32
    float* out_c  = out_ht + SZ_BH;                // [B,H] f32

    const int TB = 256;
    pack_all<<<S5 / TB, TB, 0, stream>>>(x_f, h0_f, wih_f, whh_f, w1_f, w2_f,
                                         xh, wcat, w116, w216);
    prep_small<<<(4 * H_DIM) / TB, TB, 0, stream>>>(bih_f, bhh_f, ts_f, bsum, dtv, 4 * H_DIM, B_DIM);

    dim3 gBig(4 * H_DIM / 128, B_DIM / 128);   // (32,32) = 1024 blocks
    dim3 gSm(H_DIM / 128, B_DIM / 64);         // (8,64)  = 512 blocks
    const int cellBlocks = (int)(SZ_BH / 8 / TB);

    // cell 1: gates = [x|h0] @ [Wih|Whh]^T + (b_ih+b_hh); h1 -> xh (strided), c1 -> f32 ws
    gemm2<0, 128, 128><<<gBig, TB, 0, stream>>>(xh, wcat, B_DIM, 4 * H_DIM, KCAT, bsum,
                                                gates, nullptr, nullptr, nullptr, nullptr, nullptr, 0.f, 0.f, 0);
    cellk<<<cellBlocks, TB, 0, stream>>>(gates, c0_f, xh, KCAT, IN_DIM, c1f, B_DIM, H_DIM);
    // cell 2: gates = [x|h1] @ [Wih|Whh]^T + b; h2 -> bf16 ws, c2 -> d_out (f32)
    gemm2<0, 128, 128><<<gBig, TB, 0, stream>>>(xh, wcat, B_DIM, 4 * H_DIM, KCAT, bsum,
                                                gates, nullptr, nullptr, nullptr, nullptr, nullptr, 0.f, 0.f, 0);
    cellk<<<cellBlocks, TB, 0, stream>>>(gates, c1f, h2, H_DIM, 0, out_c, B_DIM, H_DIM);

    // RK4: f(y) = tanh(y@W1^T+b1)@W2^T + b2
    // stage 1
    gemm2<1, 64, 128><<<gSm, TB, 0, stream>>>(h2, w116, B_DIM, H_DIM, H_DIM, b1_f,
                                              ubuf, nullptr, nullptr, nullptr, nullptr, nullptr, 0.f, 0.f, 0);
    gemm2<2, 64, 128><<<gSm, TB, 0, stream>>>(ubuf, w216, B_DIM, H_DIM, H_DIM, b2_f,
                                              nullptr, nullptr, h2, dtv, S, ybuf, 0.5f, 1.0f, 1);
    // stage 2
    gemm2<1, 64, 128><<<gSm, TB, 0, stream>>>(ybuf, w116, B_DIM, H_DIM, H_DIM, b1_f,
                                              ubuf, nullptr, nullptr, nullptr, nullptr, nullptr, 0.f, 0.f, 0);
    gemm2<2, 64, 128><<<gSm, TB, 0, stream>>>(ubuf, w216, B_DIM, H_DIM, H_DIM, b2_f,
                                              nullptr, nullptr, h2, dtv, S, ybuf, 0.5f, 2.0f, 0);
    // stage 3
    gemm2<1, 64, 128><<<gSm, TB, 0, stream>>>(ybuf, w116, B_DIM, H_DIM, H_DIM, b1_f,
                                              ubuf, nullptr, nullptr, nullptr, nullptr, nullptr, 0.f, 0.f, 0);
    gemm2<2, 64, 128><<<gSm, TB, 0, stream>>>(ubuf, w216, B_DIM, H_DIM, H_DIM, b2_f,
                                              nullptr, nullptr, h2, dtv, S, ybuf, 1.0f, 2.0f, 0);
    // stage 4 (final): ht -> d_out (f32)
    gemm2<1, 64, 128><<<gSm, TB, 0, stream>>>(ybuf, w116, B_DIM, H_DIM, H_DIM, b1_f,
                                              ubuf, nullptr, nullptr, nullptr, nullptr, nullptr, 0.f, 0.f, 0);
    gemm2<3, 64, 128><<<gSm, TB, 0, stream>>>(ubuf, w216, B_DIM, H_DIM, H_DIM, b2_f,
                                              nullptr, out_ht, h2, dtv, S, nullptr, 0.f, 0.f, 0);
}

// Round 8
// 420.777 us; speedup vs baseline: 1.4392x; 1.0784x over previous
//
#include <hip/hip_runtime.h>

// ---------- types ----------
typedef short short8 __attribute__((ext_vector_type(8)));     // 8 bf16 bit-patterns (4 VGPRs) - MFMA A/B frag
typedef float f32x4 __attribute__((ext_vector_type(4)));      // MFMA C/D frag
typedef unsigned short u16x8 __attribute__((ext_vector_type(8)));

#define B_DIM 4096
#define IN_DIM 512
#define H_DIM 1024
#define KCAT 1536   // IN_DIM + H_DIM

__device__ __forceinline__ float bs2f(unsigned short s) {
    return __uint_as_float(((unsigned int)s) << 16);
}
__device__ __forceinline__ unsigned short f2bs(float f) {
    unsigned int u = __float_as_uint(f);
    u += 0x7fff + ((u >> 16) & 1);   // RNE
    return (unsigned short)(u >> 16);
}
__device__ __forceinline__ float sigm(float x) { return 1.0f / (1.0f + __expf(-x)); }
__device__ __forceinline__ float ftanh(float x) { return 1.0f - 2.0f / (__expf(2.0f * x) + 1.0f); }

// ---------- fused f32 -> bf16 pack of all 6 operand segments ----------
#define S0 262144    // x    [4096,512]  -> xh   (ld 1536, off 0)
#define S1 786432    // h0   [4096,1024] -> xh   (ld 1536, off 512)
#define S2 1048576   // wih  [4096,512]  -> wcat (ld 1536, off 0)
#define S3 1572864   // whh  [4096,1024] -> wcat (ld 1536, off 512)
#define S4 1703936   // w1   [1024,1024] -> w116
#define S5 1835008   // w2   [1024,1024] -> w216
__device__ __forceinline__ void packseg(const float* __restrict__ in, long gl,
                                        int width, int ld, int off,
                                        unsigned short* __restrict__ out) {
    long i = gl * 8;
    int r = (int)(i / width);
    int c = (int)(i % width);     // width % 8 == 0 -> all 8 in-row
    float4 a = *(const float4*)(in + i);
    float4 b = *(const float4*)(in + i + 4);
    u16x8 o;
    o[0] = f2bs(a.x); o[1] = f2bs(a.y); o[2] = f2bs(a.z); o[3] = f2bs(a.w);
    o[4] = f2bs(b.x); o[5] = f2bs(b.y); o[6] = f2bs(b.z); o[7] = f2bs(b.w);
    *(u16x8*)(out + (size_t)r * ld + off + c) = o;
}
__global__ __launch_bounds__(256) void pack_all(const float* __restrict__ x,
                                                const float* __restrict__ h0,
                                                const float* __restrict__ wih,
                                                const float* __restrict__ whh,
                                                const float* __restrict__ w1,
                                                const float* __restrict__ w2,
                                                unsigned short* __restrict__ xh,
                                                unsigned short* __restrict__ wcat,
                                                unsigned short* __restrict__ w116,
                                                unsigned short* __restrict__ w216) {
    long g = (long)blockIdx.x * 256 + threadIdx.x;
    if (g < S0)       packseg(x,   g,      IN_DIM, KCAT, 0,      xh);
    else if (g < S1)  packseg(h0,  g - S0, H_DIM,  KCAT, IN_DIM, xh);
    else if (g < S2)  packseg(wih, g - S1, IN_DIM, KCAT, 0,      wcat);
    else if (g < S3)  packseg(whh, g - S2, H_DIM,  KCAT, IN_DIM, wcat);
    else if (g < S4)  packseg(w1,  g - S3, H_DIM,  H_DIM, 0,     w116);
    else if (g < S5)  packseg(w2,  g - S4, H_DIM,  H_DIM, 0,     w216);
}

// ---------- bias sum + dt ----------
__global__ __launch_bounds__(256) void prep_small(const float* __restrict__ bih,
                                                  const float* __restrict__ bhh,
                                                  const float* __restrict__ ts,
                                                  float* __restrict__ bsum,
                                                  float* __restrict__ dtv,
                                                  int n4h, int nb) {
    int i = blockIdx.x * blockDim.x + threadIdx.x;
    if (i < n4h) bsum[i] = bih[i] + bhh[i];
    if (i < nb)  dtv[i] = ts[2 * i + 1] - ts[2 * i];
}

// ---------- LSTM cell elementwise: c path in f32, h out bf16 (strided), c out f32 ----------
__global__ __launch_bounds__(256) void cellk(const unsigned short* __restrict__ gates, // [B,4H] bf16
                                             const float* __restrict__ c_in,           // [B,H] f32
                                             unsigned short* __restrict__ h_out,       // strided bf16
                                             int h_ld, int h_off,
                                             float* __restrict__ c_out,                // [B,H] f32
                                             int Bn, int Hn) {
    int tid = blockIdx.x * blockDim.x + threadIdx.x;
    long e = (long)tid * 8;
    if (e >= (long)Bn * Hn) return;
    int b = (int)(e / Hn);
    int j = (int)(e % Hn);
    const unsigned short* g0 = gates + (size_t)b * 4 * Hn + j;
    u16x8 gi = *(const u16x8*)(g0);
    u16x8 gf = *(const u16x8*)(g0 + Hn);
    u16x8 gg = *(const u16x8*)(g0 + 2 * Hn);
    u16x8 go = *(const u16x8*)(g0 + 3 * Hn);
    float4 ca = *(const float4*)(c_in + e);
    float4 cb = *(const float4*)(c_in + e + 4);
    float cin[8] = {ca.x, ca.y, ca.z, ca.w, cb.x, cb.y, cb.z, cb.w};
    u16x8 ho;
    float co[8];
    #pragma unroll
    for (int q = 0; q < 8; ++q) {
        float iv = sigm(bs2f(gi[q]));
        float fv = sigm(bs2f(gf[q]));
        float gv = ftanh(bs2f(gg[q]));
        float ov = sigm(bs2f(go[q]));
        float cn = fv * cin[q] + iv * gv;
        float hn = ov * ftanh(cn);
        ho[q] = f2bs(hn);
        co[q] = cn;
    }
    *(u16x8*)(h_out + (size_t)b * h_ld + h_off + j) = ho;
    *(float4*)(c_out + e) = make_float4(co[0], co[1], co[2], co[3]);
    *(float4*)(c_out + e + 4) = make_float4(co[4], co[5], co[6], co[7]);
}

// ---------- GEMM: C[m,n] = sum_k A[m,k]*W[n,k]  (A:[M,K], W:[N,K], both bf16) ----------
// Counted-vmcnt 2-deep prefetch (T3/T4). No XCD swizzle: with gridDim.x % 8 == 0 the
// default round-robin dispatch already pins each XCD to a fixed set of bx columns
// (bx mod 8 == XCD), giving ideal per-XCD L2 reuse of the B panels (round-7 lesson:
// contiguous-chunk swizzle DOUBLED fetch traffic here).
// EPI: 0 = bf16(acc+bias) -> outb
//      1 = bf16(tanh(acc+bias)) -> outb
//      2 = k=acc+bias; S=(first?0:S)+cw*k; ynext=bf16(h+alpha*dt*k)
//      3 = k=acc+bias; outf=f32(h + dt/6*(S+k))
#define BKt 32

template <int EPI, int BM, int BN>
__global__ __launch_bounds__(256) void gemm2(
    const unsigned short* __restrict__ A,
    const unsigned short* __restrict__ W,
    const int M, const int N, const int K,
    const float* __restrict__ bias,
    unsigned short* __restrict__ outb,
    float* __restrict__ outf,
    const unsigned short* __restrict__ hmat,
    const float* __restrict__ dtv,
    float* __restrict__ S,
    unsigned short* __restrict__ ynext,
    const float alpha, const float cw, const int first) {
    constexpr int WM = BM / 2;        // rows per wave (2x2 wave grid)
    constexpr int WN = BN / 2;        // cols per wave
    constexpr int MR = WM / 16;
    constexpr int NR = WN / 16;
    constexpr int ALOADS = BM * BKt / 8 / 256;   // 16B loads per thread for A
    constexpr int BLOADS = BN * BKt / 8 / 256;
    constexpr int LIF = ALOADS + BLOADS;         // loads in flight per stage

    __shared__ unsigned short lA[2][BM * BKt];
    __shared__ unsigned short lB[2][BN * BKt];
    const int t = threadIdx.x;
    const int lane = t & 63;
    const int wave = t >> 6;
    const int wm = (wave >> 1) * WM;
    const int wn = (wave & 1) * WN;
    const int fr = lane & 15;
    const int kb = lane >> 4;
    const int tile_m = blockIdx.y * BM;
    const int tile_n = blockIdx.x * BN;

    f32x4 acc[MR][NR];
    #pragma unroll
    for (int i = 0; i < MR; ++i)
        #pragma unroll
        for (int j = 0; j < NR; ++j)
            acc[i][j] = (f32x4){0.f, 0.f, 0.f, 0.f};

    const unsigned short* aptr = A + (size_t)tile_m * K;
    const unsigned short* wptr = W + (size_t)tile_n * K;

    auto stage = [&](int buf, int k0) {
        #pragma unroll
        for (int j = 0; j < ALOADS; ++j) {
            int idx = j * 256 + t;
            int row = idx >> 2;
            int col = (idx & 3) * 8;
            __builtin_amdgcn_global_load_lds(
                (__attribute__((address_space(1))) void*)(aptr + (size_t)row * K + k0 + col),
                (__attribute__((address_space(3))) void*)(&lA[buf][idx * 8]), 16, 0, 0);
        }
        #pragma unroll
        for (int j = 0; j < BLOADS; ++j) {
            int idx = j * 256 + t;
            int row = idx >> 2;
            int col = (idx & 3) * 8;
            __builtin_amdgcn_global_load_lds(
                (__attribute__((address_space(1))) void*)(wptr + (size_t)row * K + k0 + col),
                (__attribute__((address_space(3))) void*)(&lB[buf][idx * 8]), 16, 0, 0);
        }
    };

    const int NT = K / BKt;
    stage(0, 0);
    if (NT > 1) stage(1, BKt);
    int cur = 0;
    for (int kt = 0; kt < NT; ++kt) {
        // wait own oldest stage (tile kt) landed; newer stage (kt+1) stays in flight
        if (kt + 1 < NT) {
            if constexpr (LIF == 2) asm volatile("s_waitcnt vmcnt(2)" ::: "memory");
            else if constexpr (LIF == 3) asm volatile("s_waitcnt vmcnt(3)" ::: "memory");
            else if constexpr (LIF == 4) asm volatile("s_waitcnt vmcnt(4)" ::: "memory");
            else if constexpr (LIF == 6) asm volatile("s_waitcnt vmcnt(6)" ::: "memory");
            else asm volatile("s_waitcnt vmcnt(0)" ::: "memory");
        } else {
            asm volatile("s_waitcnt vmcnt(0)" ::: "memory");
        }
        __builtin_amdgcn_s_barrier();      // all waves' stage(kt) complete -> buf cur readable
        short8 af[MR], bfr[NR];
        #pragma unroll
        for (int i = 0; i < MR; ++i)
            af[i] = *(const short8*)&lA[cur][(wm + i * 16 + fr) * BKt + kb * 8];
        #pragma unroll
        for (int j = 0; j < NR; ++j)
            bfr[j] = *(const short8*)&lB[cur][(wn + j * 16 + fr) * BKt + kb * 8];
        #pragma unroll
        for (int i = 0; i < MR; ++i)
            #pragma unroll
            for (int j = 0; j < NR; ++j)
                acc[i][j] = __builtin_amdgcn_mfma_f32_16x16x32_bf16(af[i], bfr[j], acc[i][j], 0, 0, 0);
        asm volatile("" ::: "memory");     // pin ds_reads before the barrier
        __builtin_amdgcn_s_barrier();      // all waves done reading buf cur
        if (kt + 2 < NT) stage(cur, (kt + 2) * BKt);   // overwrite just-freed buffer
        cur ^= 1;
    }

    // epilogue: D element (col = lane&15 -> n, row = (lane>>4)*4+r -> m)
    #pragma unroll
    for (int i = 0; i < MR; ++i) {
        #pragma unroll
        for (int r = 0; r < 4; ++r) {
            const int m = tile_m + wm + i * 16 + kb * 4 + r;
            float dt = 0.f;
            if (EPI >= 2) dt = dtv[m];
            #pragma unroll
            for (int j = 0; j < NR; ++j) {
                const int n = tile_n + wn + j * 16 + fr;
                const size_t off = (size_t)m * N + n;
                float v = acc[i][j][r];
                if (bias) v += bias[n];
                if (EPI == 0) {
                    outb[off] = f2bs(v);
                } else if (EPI == 1) {
                    outb[off] = f2bs(ftanh(v));
                } else if (EPI == 2) {
                    float hv = bs2f(hmat[off]);
                    float s = first ? 0.f : S[off];
                    S[off] = s + cw * v;
                    ynext[off] = f2bs(hv + alpha * dt * v);
                } else { // EPI == 3: final ht, f32 output
                    float hv = bs2f(hmat[off]);
                    outf[off] = hv + (dt * (1.0f / 6.0f)) * (S[off] + v);
                }
            }
        }
    }
}

// ---------- launch ----------
extern "C" void kernel_launch(void* const* d_in, const int* in_sizes, int n_in,
                              void* d_out, int out_size, void* d_ws, size_t ws_size,
                              hipStream_t stream) {
    int IX = 0, IH0 = 1, IC0 = 2, ITS = 3, IWIH = 4, IWHH = 5, IBIH = 6, IBHH = 7,
        IW1 = 8, IB1 = 9, IW2 = 10, IB2 = 11;
    const bool sorted_ok = n_in >= 12 &&
        in_sizes[0] == 1024 && in_sizes[1] == 1024 && in_sizes[2] == 4096 &&
        in_sizes[3] == 4096 && in_sizes[4] == 4194304 && in_sizes[5] == 4194304 &&
        in_sizes[6] == 2097152 && in_sizes[7] == 8192 && in_sizes[8] == 1048576 &&
        in_sizes[9] == 1048576 && in_sizes[10] == 4194304 && in_sizes[11] == 2097152;
    if (sorted_ok) { // b1,b2,b_hh,b_ih,c0,h0,inputs,ts,w1,w2,w_hh,w_ih
        IB1 = 0; IB2 = 1; IBHH = 2; IBIH = 3; IC0 = 4; IH0 = 5;
        IX = 6; ITS = 7; IW1 = 8; IW2 = 9; IWHH = 10; IWIH = 11;
    }
    const float* x_f   = (const float*)d_in[IX];
    const float* h0_f  = (const float*)d_in[IH0];
    const float* c0_f  = (const float*)d_in[IC0];
    const float* ts_f  = (const float*)d_in[ITS];
    const float* wih_f = (const float*)d_in[IWIH];
    const float* whh_f = (const float*)d_in[IWHH];
    const float* bih_f = (const float*)d_in[IBIH];
    const float* bhh_f = (const float*)d_in[IBHH];
    const float* w1_f  = (const float*)d_in[IW1];
    const float* b1_f  = (const float*)d_in[IB1];
    const float* w2_f  = (const float*)d_in[IW2];
    const float* b2_f  = (const float*)d_in[IB2];

    constexpr size_t SZ_BH   = (size_t)B_DIM * H_DIM;        // 4M
    constexpr size_t SZ_B4H  = (size_t)B_DIM * 4 * H_DIM;    // 16M
    constexpr size_t SZ_HH   = (size_t)H_DIM * H_DIM;        // 1M
    constexpr size_t SZ_WCAT = (size_t)4 * H_DIM * KCAT;     // 6M
    constexpr size_t SZ_XH   = (size_t)B_DIM * KCAT;         // 6M

    // workspace (~101 MB): f32 regions first, then bf16
    float* bsum = (float*)d_ws;                    // 4H
    float* dtv  = bsum + 4 * H_DIM;                // B
    float* S    = dtv + B_DIM;                     // [B,H] f32 (16 MB)
    float* c1f  = S + SZ_BH;                       // [B,H] f32 (16 MB)
    unsigned short* wcat  = (unsigned short*)(c1f + SZ_BH);  // [4H,KCAT]
    unsigned short* w116  = wcat + SZ_WCAT;
    unsigned short* w216  = w116 + SZ_HH;
    unsigned short* xh    = w216 + SZ_HH;          // [B,KCAT]
    unsigned short* h2    = xh + SZ_XH;            // [B,H]
    unsigned short* gates = h2 + SZ_BH;            // [B,4H] (dead after cellk2)
    unsigned short* ubuf  = gates;                 // alias: RK4 u
    unsigned short* ybuf  = gates + SZ_BH;         // alias: RK4 y

    float* out_ht = (float*)d_out;                 // [B,H] f32
    float* out_c  = out_ht + SZ_BH;                // [B,H] f32

    const int TB = 256;
    pack_all<<<S5 / TB, TB, 0, stream>>>(x_f, h0_f, wih_f, whh_f, w1_f, w2_f,
                                         xh, wcat, w116, w216);
    prep_small<<<(4 * H_DIM) / TB, TB, 0, stream>>>(bih_f, bhh_f, ts_f, bsum, dtv, 4 * H_DIM, B_DIM);

    dim3 gBig(4 * H_DIM / 128, B_DIM / 128);   // (32,32) = 1024 blocks
    dim3 gSm(H_DIM / 64, B_DIM / 64);          // (16,64) = 1024 blocks, 4/CU
    const int cellBlocks = (int)(SZ_BH / 8 / TB);

    // cell 1: gates = [x|h0] @ [Wih|Whh]^T + (b_ih+b_hh); h1 -> xh (strided), c1 -> f32 ws
    gemm2<0, 128, 128><<<gBig, TB, 0, stream>>>(xh, wcat, B_DIM, 4 * H_DIM, KCAT, bsum,
                                                gates, nullptr, nullptr, nullptr, nullptr, nullptr, 0.f, 0.f, 0);
    cellk<<<cellBlocks, TB, 0, stream>>>(gates, c0_f, xh, KCAT, IN_DIM, c1f, B_DIM, H_DIM);
    // cell 2: gates = [x|h1] @ [Wih|Whh]^T + b; h2 -> bf16 ws, c2 -> d_out (f32)
    gemm2<0, 128, 128><<<gBig, TB, 0, stream>>>(xh, wcat, B_DIM, 4 * H_DIM, KCAT, bsum,
                                                gates, nullptr, nullptr, nullptr, nullptr, nullptr, 0.f, 0.f, 0);
    cellk<<<cellBlocks, TB, 0, stream>>>(gates, c1f, h2, H_DIM, 0, out_c, B_DIM, H_DIM);

    // RK4: f(y) = tanh(y@W1^T+b1)@W2^T + b2
    // stage 1
    gemm2<1, 64, 64><<<gSm, TB, 0, stream>>>(h2, w116, B_DIM, H_DIM, H_DIM, b1_f,
                                             ubuf, nullptr, nullptr, nullptr, nullptr, nullptr, 0.f, 0.f, 0);
    gemm2<2, 64, 64><<<gSm, TB, 0, stream>>>(ubuf, w216, B_DIM, H_DIM, H_DIM, b2_f,
                                             nullptr, nullptr, h2, dtv, S, ybuf, 0.5f, 1.0f, 1);
    // stage 2
    gemm2<1, 64, 64><<<gSm, TB, 0, stream>>>(ybuf, w116, B_DIM, H_DIM, H_DIM, b1_f,
                                             ubuf, nullptr, nullptr, nullptr, nullptr, nullptr, 0.f, 0.f, 0);
    gemm2<2, 64, 64><<<gSm, TB, 0, stream>>>(ubuf, w216, B_DIM, H_DIM, H_DIM, b2_f,
                                             nullptr, nullptr, h2, dtv, S, ybuf, 0.5f, 2.0f, 0);
    // stage 3
    gemm2<1, 64, 64><<<gSm, TB, 0, stream>>>(ybuf, w116, B_DIM, H_DIM, H_DIM, b1_f,
                                             ubuf, nullptr, nullptr, nullptr, nullptr, nullptr, 0.f, 0.f, 0);
    gemm2<2, 64, 64><<<gSm, TB, 0, stream>>>(ubuf, w216, B_DIM, H_DIM, H_DIM, b2_f,
                                             nullptr, nullptr, h2, dtv, S, ybuf, 1.0f, 2.0f, 0);
    // stage 4 (final): ht -> d_out (f32)
    gemm2<1, 64, 64><<<gSm, TB, 0, stream>>>(ybuf, w116, B_DIM, H_DIM, H_DIM, b1_f,
                                             ubuf, nullptr, nullptr, nullptr, nullptr, nullptr, 0.f, 0.f, 0);
    gemm2<3, 64, 64><<<gSm, TB, 0, stream>>>(ubuf, w216, B_DIM, H_DIM, H_DIM, b2_f,
                                             nullptr, out_ht, h2, dtv, S, nullptr, 0.f, 0.f, 0);
}

// Round 9
// 366.287 us; speedup vs baseline: 1.6533x; 1.1488x over previous
//
#include <hip/hip_runtime.h>

// ---------- types ----------
typedef short short8 __attribute__((ext_vector_type(8)));     // 8 bf16 bit-patterns (4 VGPRs) - MFMA A/B frag
typedef float f32x4 __attribute__((ext_vector_type(4)));      // MFMA C/D frag
typedef unsigned short u16x8 __attribute__((ext_vector_type(8)));

#define B_DIM 4096
#define IN_DIM 512
#define H_DIM 1024
#define KCAT 1536   // IN_DIM + H_DIM

__device__ __forceinline__ float bs2f(unsigned short s) {
    return __uint_as_float(((unsigned int)s) << 16);
}
__device__ __forceinline__ unsigned short f2bs(float f) {
    unsigned int u = __float_as_uint(f);
    u += 0x7fff + ((u >> 16) & 1);   // RNE
    return (unsigned short)(u >> 16);
}
__device__ __forceinline__ float sigm(float x) { return 1.0f / (1.0f + __expf(-x)); }
__device__ __forceinline__ float ftanh(float x) { return 1.0f - 2.0f / (__expf(2.0f * x) + 1.0f); }

// gate-interleave permutation: orig gate row r (g=r>>10, j=r&1023) -> n' = (j>>4)*64 + g*16 + (j&15)
// With this layout a wave's 64-wide n-window = {4 gates} x {16 consecutive j}: lane fr's
// acc[i][0..3][r] are the 4 gate pre-activations of one (m, j) -> LSTM cell fuses into epilogue.
__device__ __forceinline__ int gperm(int r) {
    int g = r >> 10, j = r & 1023;
    return ((j >> 4) << 6) + (g << 4) + (j & 15);
}

// ---------- fused f32 -> bf16 pack: xb, hb0 flat; wih/whh gate-interleaved into wcat; w1,w2 flat ----------
#define T0 262144    // x    [4096,512]  -> xb flat
#define T1 786432    // h0   [4096,1024] -> hb0 flat
#define T2 1048576   // wih  [4096,512]  -> wcat interleaved rows, col off 0
#define T3 1572864   // whh  [4096,1024] -> wcat interleaved rows, col off 512
#define T4 1703936   // w1   [1024,1024] -> w116 flat
#define T5 1835008   // w2   [1024,1024] -> w216 flat
__device__ __forceinline__ u16x8 cvt8(const float* __restrict__ in, long i) {
    float4 a = *(const float4*)(in + i);
    float4 b = *(const float4*)(in + i + 4);
    u16x8 o;
    o[0] = f2bs(a.x); o[1] = f2bs(a.y); o[2] = f2bs(a.z); o[3] = f2bs(a.w);
    o[4] = f2bs(b.x); o[5] = f2bs(b.y); o[6] = f2bs(b.z); o[7] = f2bs(b.w);
    return o;
}
__global__ __launch_bounds__(256) void pack_all(const float* __restrict__ x,
                                                const float* __restrict__ h0,
                                                const float* __restrict__ wih,
                                                const float* __restrict__ whh,
                                                const float* __restrict__ w1,
                                                const float* __restrict__ w2,
                                                unsigned short* __restrict__ xb,
                                                unsigned short* __restrict__ hb0,
                                                unsigned short* __restrict__ wcat,
                                                unsigned short* __restrict__ w116,
                                                unsigned short* __restrict__ w216) {
    long g = (long)blockIdx.x * 256 + threadIdx.x;
    if (g < T0) {
        long i = g * 8;
        *(u16x8*)(xb + i) = cvt8(x, i);
    } else if (g < T1) {
        long i = (g - T0) * 8;
        *(u16x8*)(hb0 + i) = cvt8(h0, i);
    } else if (g < T2) {
        long i = (g - T1) * 8;
        int r = (int)(i / IN_DIM), c = (int)(i % IN_DIM);
        *(u16x8*)(wcat + (size_t)gperm(r) * KCAT + c) = cvt8(wih, i);
    } else if (g < T3) {
        long i = (g - T2) * 8;
        int r = (int)(i / H_DIM), c = (int)(i % H_DIM);
        *(u16x8*)(wcat + (size_t)gperm(r) * KCAT + IN_DIM + c) = cvt8(whh, i);
    } else if (g < T4) {
        long i = (g - T3) * 8;
        *(u16x8*)(w116 + i) = cvt8(w1, i);
    } else if (g < T5) {
        long i = (g - T4) * 8;
        *(u16x8*)(w216 + i) = cvt8(w2, i);
    }
}

// ---------- bias sum (gate-permuted) + dt ----------
__global__ __launch_bounds__(256) void prep_small(const float* __restrict__ bih,
                                                  const float* __restrict__ bhh,
                                                  const float* __restrict__ ts,
                                                  float* __restrict__ bsum,
                                                  float* __restrict__ dtv,
                                                  int n4h, int nb) {
    int i = blockIdx.x * blockDim.x + threadIdx.x;
    if (i < n4h) bsum[gperm(i)] = bih[i] + bhh[i];
    if (i < nb)  dtv[i] = ts[2 * i + 1] - ts[2 * i];
}

// ---------- GEMM: C[m,n] = sum_k A[m,k]*W[n,k] ----------
// Counted-vmcnt 2-deep prefetch. No XCD swizzle (round-7: default round-robin dispatch already
// gives per-XCD B-panel L2 affinity when gridDim.x % 8 == 0; chunked swizzle doubled fetch).
// SPLIT: A = [xb (stride 512) | hb (stride 1024)] split at k=512 (gates); else single A1.
// EPI: 1 = bf16(tanh(acc+bias)) -> outb            (RK4 u)
//      2 = k=acc+bias; S=(first?0:S)+cw*k; ynext=bf16(h+alpha*dt*k)
//      3 = k=acc+bias; outf=f32(h + dt/6*(S+k))    (final ht)
//      4 = fused LSTM cell (needs gate-interleaved W; writes h bf16 + c f32)
#define BKt 32

template <int EPI, int BM, int BN, bool SPLIT>
__global__ __launch_bounds__(256) void gemm2(
    const unsigned short* __restrict__ A0,   // x part (stride IN_DIM) when SPLIT
    const unsigned short* __restrict__ A1,   // h part (stride H_DIM) / full A
    const unsigned short* __restrict__ W,
    const int M, const int N, const int K,
    const float* __restrict__ bias,
    unsigned short* __restrict__ outb,
    float* __restrict__ outf,
    const float* __restrict__ c_in,          // EPI4: f32 c state
    const unsigned short* __restrict__ hmat, // EPI2/3: bf16 h2
    const float* __restrict__ dtv,
    float* __restrict__ S,
    unsigned short* __restrict__ ynext,
    const float alpha, const float cw, const int first) {
    constexpr int WM = BM / 2;        // rows per wave (2x2 wave grid)
    constexpr int WN = BN / 2;        // cols per wave (must be 64 for EPI4)
    constexpr int MR = WM / 16;
    constexpr int NR = WN / 16;
    constexpr int ALOADS = BM * BKt / 8 / 256;
    constexpr int BLOADS = BN * BKt / 8 / 256;
    constexpr int LIF = ALOADS + BLOADS;

    __shared__ unsigned short lA[2][BM * BKt];
    __shared__ unsigned short lB[2][BN * BKt];
    const int t = threadIdx.x;
    const int lane = t & 63;
    const int wave = t >> 6;
    const int wm = (wave >> 1) * WM;
    const int wn = (wave & 1) * WN;
    const int fr = lane & 15;
    const int kb = lane >> 4;
    const int tile_m = blockIdx.y * BM;
    const int tile_n = blockIdx.x * BN;

    f32x4 acc[MR][NR];
    #pragma unroll
    for (int i = 0; i < MR; ++i)
        #pragma unroll
        for (int j = 0; j < NR; ++j)
            acc[i][j] = (f32x4){0.f, 0.f, 0.f, 0.f};

    const unsigned short* aptr0 = SPLIT ? A0 + (size_t)tile_m * IN_DIM : nullptr;
    const unsigned short* aptr1 = A1 + (size_t)tile_m * (SPLIT ? H_DIM : K);
    const unsigned short* wptr  = W + (size_t)tile_n * K;

    auto stage = [&](int buf, int k0) {
        #pragma unroll
        for (int j = 0; j < ALOADS; ++j) {
            int idx = j * 256 + t;
            int row = idx >> 2;
            int col = (idx & 3) * 8;
            const unsigned short* src;
            if constexpr (SPLIT) {
                if (k0 < IN_DIM) src = aptr0 + (size_t)row * IN_DIM + k0 + col;
                else             src = aptr1 + (size_t)row * H_DIM + (k0 - IN_DIM) + col;
            } else {
                src = aptr1 + (size_t)row * K + k0 + col;
            }
            __builtin_amdgcn_global_load_lds(
                (__attribute__((address_space(1))) void*)src,
                (__attribute__((address_space(3))) void*)(&lA[buf][idx * 8]), 16, 0, 0);
        }
        #pragma unroll
        for (int j = 0; j < BLOADS; ++j) {
            int idx = j * 256 + t;
            int row = idx >> 2;
            int col = (idx & 3) * 8;
            __builtin_amdgcn_global_load_lds(
                (__attribute__((address_space(1))) void*)(wptr + (size_t)row * K + k0 + col),
                (__attribute__((address_space(3))) void*)(&lB[buf][idx * 8]), 16, 0, 0);
        }
    };

    const int NT = K / BKt;
    stage(0, 0);
    if (NT > 1) stage(1, BKt);
    int cur = 0;
    for (int kt = 0; kt < NT; ++kt) {
        if (kt + 1 < NT) {
            if constexpr (LIF == 2) asm volatile("s_waitcnt vmcnt(2)" ::: "memory");
            else if constexpr (LIF == 3) asm volatile("s_waitcnt vmcnt(3)" ::: "memory");
            else if constexpr (LIF == 4) asm volatile("s_waitcnt vmcnt(4)" ::: "memory");
            else if constexpr (LIF == 6) asm volatile("s_waitcnt vmcnt(6)" ::: "memory");
            else asm volatile("s_waitcnt vmcnt(0)" ::: "memory");
        } else {
            asm volatile("s_waitcnt vmcnt(0)" ::: "memory");
        }
        __builtin_amdgcn_s_barrier();      // all waves' stage(kt) complete
        short8 af[MR], bfr[NR];
        #pragma unroll
        for (int i = 0; i < MR; ++i)
            af[i] = *(const short8*)&lA[cur][(wm + i * 16 + fr) * BKt + kb * 8];
        #pragma unroll
        for (int j = 0; j < NR; ++j)
            bfr[j] = *(const short8*)&lB[cur][(wn + j * 16 + fr) * BKt + kb * 8];
        #pragma unroll
        for (int i = 0; i < MR; ++i)
            #pragma unroll
            for (int j = 0; j < NR; ++j)
                acc[i][j] = __builtin_amdgcn_mfma_f32_16x16x32_bf16(af[i], bfr[j], acc[i][j], 0, 0, 0);
        asm volatile("" ::: "memory");
        __builtin_amdgcn_s_barrier();      // all waves done reading buf cur
        if (kt + 2 < NT) stage(cur, (kt + 2) * BKt);
        cur ^= 1;
    }

    // epilogue: D element (col = lane&15 -> n, row = (lane>>4)*4+r -> m)
    const int H = N >> 2;                  // EPI4: output width (N = 4H)
    const int jbase = ((tile_n + wn) >> 6) << 4;
    #pragma unroll
    for (int i = 0; i < MR; ++i) {
        #pragma unroll
        for (int r = 0; r < 4; ++r) {
            const int m = tile_m + wm + i * 16 + kb * 4 + r;
            float dt = 0.f;
            if (EPI == 2 || EPI == 3) dt = dtv[m];
            if (EPI == 4) {
                float vg[4];
                #pragma unroll
                for (int g = 0; g < 4; ++g)
                    vg[g] = acc[i][g][r] + bias[tile_n + wn + g * 16 + fr];
                const int j = jbase + fr;
                float cin = c_in[(size_t)m * H + j];
                float ig = sigm(vg[0]);
                float fg = sigm(vg[1]);
                float gg = ftanh(vg[2]);
                float og = sigm(vg[3]);
                float cn = fg * cin + ig * gg;
                float hn = og * ftanh(cn);
                outb[(size_t)m * H + j] = f2bs(hn);   // h (bf16)
                outf[(size_t)m * H + j] = cn;         // c (f32)
            } else {
                #pragma unroll
                for (int j = 0; j < NR; ++j) {
                    const int n = tile_n + wn + j * 16 + fr;
                    const size_t off = (size_t)m * N + n;
                    float v = acc[i][j][r];
                    if (bias) v += bias[n];
                    if (EPI == 1) {
                        outb[off] = f2bs(ftanh(v));
                    } else if (EPI == 2) {
                        float hv = bs2f(hmat[off]);
                        float s = first ? 0.f : S[off];
                        S[off] = s + cw * v;
                        ynext[off] = f2bs(hv + alpha * dt * v);
                    } else { // EPI == 3
                        float hv = bs2f(hmat[off]);
                        outf[off] = hv + (dt * (1.0f / 6.0f)) * (S[off] + v);
                    }
                }
            }
        }
    }
}

// ---------- launch ----------
extern "C" void kernel_launch(void* const* d_in, const int* in_sizes, int n_in,
                              void* d_out, int out_size, void* d_ws, size_t ws_size,
                              hipStream_t stream) {
    int IX = 0, IH0 = 1, IC0 = 2, ITS = 3, IWIH = 4, IWHH = 5, IBIH = 6, IBHH = 7,
        IW1 = 8, IB1 = 9, IW2 = 10, IB2 = 11;
    const bool sorted_ok = n_in >= 12 &&
        in_sizes[0] == 1024 && in_sizes[1] == 1024 && in_sizes[2] == 4096 &&
        in_sizes[3] == 4096 && in_sizes[4] == 4194304 && in_sizes[5] == 4194304 &&
        in_sizes[6] == 2097152 && in_sizes[7] == 8192 && in_sizes[8] == 1048576 &&
        in_sizes[9] == 1048576 && in_sizes[10] == 4194304 && in_sizes[11] == 2097152;
    if (sorted_ok) { // b1,b2,b_hh,b_ih,c0,h0,inputs,ts,w1,w2,w_hh,w_ih
        IB1 = 0; IB2 = 1; IBHH = 2; IBIH = 3; IC0 = 4; IH0 = 5;
        IX = 6; ITS = 7; IW1 = 8; IW2 = 9; IWHH = 10; IWIH = 11;
    }
    const float* x_f   = (const float*)d_in[IX];
    const float* h0_f  = (const float*)d_in[IH0];
    const float* c0_f  = (const float*)d_in[IC0];
    const float* ts_f  = (const float*)d_in[ITS];
    const float* wih_f = (const float*)d_in[IWIH];
    const float* whh_f = (const float*)d_in[IWHH];
    const float* bih_f = (const float*)d_in[IBIH];
    const float* bhh_f = (const float*)d_in[IBHH];
    const float* w1_f  = (const float*)d_in[IW1];
    const float* b1_f  = (const float*)d_in[IB1];
    const float* w2_f  = (const float*)d_in[IW2];
    const float* b2_f  = (const float*)d_in[IB2];

    constexpr size_t SZ_BIN  = (size_t)B_DIM * IN_DIM;       // 2M
    constexpr size_t SZ_BH   = (size_t)B_DIM * H_DIM;        // 4M
    constexpr size_t SZ_HH   = (size_t)H_DIM * H_DIM;        // 1M
    constexpr size_t SZ_WCAT = (size_t)4 * H_DIM * KCAT;     // 6M

    // workspace (~100 MB): f32 regions first, then bf16
    float* bsum = (float*)d_ws;                    // 4H (gate-permuted)
    float* dtv  = bsum + 4 * H_DIM;                // B
    float* S    = dtv + B_DIM;                     // [B,H] f32 (16 MB)
    float* c1f  = S + SZ_BH;                       // [B,H] f32 (16 MB)
    unsigned short* wcat = (unsigned short*)(c1f + SZ_BH);   // [4H,KCAT] interleaved (12 MB)
    unsigned short* w116 = wcat + SZ_WCAT;         // 2 MB
    unsigned short* w216 = w116 + SZ_HH;           // 2 MB
    unsigned short* xb   = w216 + SZ_HH;           // [B,512]  4 MB
    unsigned short* hb0  = xb + SZ_BIN;            // [B,H] 8 MB
    unsigned short* hb1  = hb0 + SZ_BH;            // [B,H] 8 MB
    unsigned short* hb2  = hb1 + SZ_BH;            // [B,H] 8 MB
    unsigned short* ubuf = hb2 + SZ_BH;            // [B,H] 8 MB
    unsigned short* ybuf = ubuf + SZ_BH;           // [B,H] 8 MB

    float* out_ht = (float*)d_out;                 // [B,H] f32
    float* out_c  = out_ht + SZ_BH;                // [B,H] f32

    const int TB = 256;
    pack_all<<<T5 / TB, TB, 0, stream>>>(x_f, h0_f, wih_f, whh_f, w1_f, w2_f,
                                         xb, hb0, wcat, w116, w216);
    prep_small<<<(4 * H_DIM) / TB, TB, 0, stream>>>(bih_f, bhh_f, ts_f, bsum, dtv, 4 * H_DIM, B_DIM);

    dim3 gBig(4 * H_DIM / 128, B_DIM / 128);   // (32,32) = 1024 blocks
    dim3 gSm(H_DIM / 64, B_DIM / 64);          // (16,64) = 1024 blocks

    // cell 1 (fused): gates GEMM + LSTM cell -> h1 (hb1), c1 (c1f). Reads hb0, writes hb1: race-free.
    // c0 is f32 input directly.
    gemm2<4, 128, 128, true><<<gBig, TB, 0, stream>>>(
        xb, hb0, wcat, B_DIM, 4 * H_DIM, KCAT, bsum,
        hb1, c1f, c0_f, nullptr, nullptr, nullptr, nullptr, 0.f, 0.f, 0);
    // cell 2 (fused): reads hb1 + c1f -> h2 (hb2), c2 -> out_c (f32)
    gemm2<4, 128, 128, true><<<gBig, TB, 0, stream>>>(
        xb, hb1, wcat, B_DIM, 4 * H_DIM, KCAT, bsum,
        hb2, out_c, c1f, nullptr, nullptr, nullptr, nullptr, 0.f, 0.f, 0);

    // RK4: f(y) = tanh(y@W1^T+b1)@W2^T + b2
    // stage 1
    gemm2<1, 64, 64, false><<<gSm, TB, 0, stream>>>(
        nullptr, hb2, w116, B_DIM, H_DIM, H_DIM, b1_f,
        ubuf, nullptr, nullptr, nullptr, nullptr, nullptr, nullptr, 0.f, 0.f, 0);
    gemm2<2, 64, 64, false><<<gSm, TB, 0, stream>>>(
        nullptr, ubuf, w216, B_DIM, H_DIM, H_DIM, b2_f,
        nullptr, nullptr, nullptr, hb2, dtv, S, ybuf, 0.5f, 1.0f, 1);
    // stage 2
    gemm2<1, 64, 64, false><<<gSm, TB, 0, stream>>>(
        nullptr, ybuf, w116, B_DIM, H_DIM, H_DIM, b1_f,
        ubuf, nullptr, nullptr, nullptr, nullptr, nullptr, nullptr, 0.f, 0.f, 0);
    gemm2<2, 64, 64, false><<<gSm, TB, 0, stream>>>(
        nullptr, ubuf, w216, B_DIM, H_DIM, H_DIM, b2_f,
        nullptr, nullptr, nullptr, hb2, dtv, S, ybuf, 0.5f, 2.0f, 0);
    // stage 3
    gemm2<1, 64, 64, false><<<gSm, TB, 0, stream>>>(
        nullptr, ybuf, w116, B_DIM, H_DIM, H_DIM, b1_f,
        ubuf, nullptr, nullptr, nullptr, nullptr, nullptr, nullptr, 0.f, 0.f, 0);
    gemm2<2, 64, 64, false><<<gSm, TB, 0, stream>>>(
        nullptr, ubuf, w216, B_DIM, H_DIM, H_DIM, b2_f,
        nullptr, nullptr, nullptr, hb2, dtv, S, ybuf, 1.0f, 2.0f, 0);
    // stage 4 (final): ht -> d_out (f32)
    gemm2<1, 64, 64, false><<<gSm, TB, 0, stream>>>(
        nullptr, ybuf, w116, B_DIM, H_DIM, H_DIM, b1_f,
        ubuf, nullptr, nullptr, nullptr, nullptr, nullptr, nullptr, 0.f, 0.f, 0);
    gemm2<3, 64, 64, false><<<gSm, TB, 0, stream>>>(
        nullptr, ubuf, w216, B_DIM, H_DIM, H_DIM, b2_f,
        nullptr, out_ht, nullptr, hb2, dtv, S, nullptr, 0.f, 0.f, 0);
}

// Round 10
// 364.574 us; speedup vs baseline: 1.6611x; 1.0047x over previous
//
#include <hip/hip_runtime.h>

// ---------- types ----------
typedef short short8 __attribute__((ext_vector_type(8)));     // 8 bf16 bit-patterns (4 VGPRs) - MFMA A/B frag
typedef float f32x4 __attribute__((ext_vector_type(4)));      // MFMA C/D frag
typedef unsigned short u16x8 __attribute__((ext_vector_type(8)));

#define B_DIM 4096
#define IN_DIM 512
#define H_DIM 1024
#define KCAT 1536   // IN_DIM + H_DIM

__device__ __forceinline__ float bs2f(unsigned short s) {
    return __uint_as_float(((unsigned int)s) << 16);
}
__device__ __forceinline__ unsigned short f2bs(float f) {
    unsigned int u = __float_as_uint(f);
    u += 0x7fff + ((u >> 16) & 1);   // RNE
    return (unsigned short)(u >> 16);
}
__device__ __forceinline__ float sigm(float x) { return 1.0f / (1.0f + __expf(-x)); }
__device__ __forceinline__ float ftanh(float x) { return 1.0f - 2.0f / (__expf(2.0f * x) + 1.0f); }

// gate-interleave permutation: orig gate row r (g=r>>10, j=r&1023) -> n' = (j>>4)*64 + g*16 + (j&15)
__device__ __forceinline__ int gperm(int r) {
    int g = r >> 10, j = r & 1023;
    return ((j >> 4) << 6) + (g << 4) + (j & 15);
}

// ---------- fused f32 -> bf16 pack: xb, hb0 flat; wih/whh gate-interleaved into wcat; w1,w2 flat ----------
#define T0 262144    // x    [4096,512]  -> xb flat
#define T1 786432    // h0   [4096,1024] -> hb0 flat
#define T2 1048576   // wih  [4096,512]  -> wcat interleaved rows, col off 0
#define T3 1572864   // whh  [4096,1024] -> wcat interleaved rows, col off 512
#define T4 1703936   // w1   [1024,1024] -> w116 flat
#define T5 1835008   // w2   [1024,1024] -> w216 flat
__device__ __forceinline__ u16x8 cvt8(const float* __restrict__ in, long i) {
    float4 a = *(const float4*)(in + i);
    float4 b = *(const float4*)(in + i + 4);
    u16x8 o;
    o[0] = f2bs(a.x); o[1] = f2bs(a.y); o[2] = f2bs(a.z); o[3] = f2bs(a.w);
    o[4] = f2bs(b.x); o[5] = f2bs(b.y); o[6] = f2bs(b.z); o[7] = f2bs(b.w);
    return o;
}
__global__ __launch_bounds__(256) void pack_all(const float* __restrict__ x,
                                                const float* __restrict__ h0,
                                                const float* __restrict__ wih,
                                                const float* __restrict__ whh,
                                                const float* __restrict__ w1,
                                                const float* __restrict__ w2,
                                                unsigned short* __restrict__ xb,
                                                unsigned short* __restrict__ hb0,
                                                unsigned short* __restrict__ wcat,
                                                unsigned short* __restrict__ w116,
                                                unsigned short* __restrict__ w216) {
    long g = (long)blockIdx.x * 256 + threadIdx.x;
    if (g < T0) {
        long i = g * 8;
        *(u16x8*)(xb + i) = cvt8(x, i);
    } else if (g < T1) {
        long i = (g - T0) * 8;
        *(u16x8*)(hb0 + i) = cvt8(h0, i);
    } else if (g < T2) {
        long i = (g - T1) * 8;
        int r = (int)(i / IN_DIM), c = (int)(i % IN_DIM);
        *(u16x8*)(wcat + (size_t)gperm(r) * KCAT + c) = cvt8(wih, i);
    } else if (g < T3) {
        long i = (g - T2) * 8;
        int r = (int)(i / H_DIM), c = (int)(i % H_DIM);
        *(u16x8*)(wcat + (size_t)gperm(r) * KCAT + IN_DIM + c) = cvt8(whh, i);
    } else if (g < T4) {
        long i = (g - T3) * 8;
        *(u16x8*)(w116 + i) = cvt8(w1, i);
    } else if (g < T5) {
        long i = (g - T4) * 8;
        *(u16x8*)(w216 + i) = cvt8(w2, i);
    }
}

// ---------- bias sum (gate-permuted) + dt ----------
__global__ __launch_bounds__(256) void prep_small(const float* __restrict__ bih,
                                                  const float* __restrict__ bhh,
                                                  const float* __restrict__ ts,
                                                  float* __restrict__ bsum,
                                                  float* __restrict__ dtv,
                                                  int n4h, int nb) {
    int i = blockIdx.x * blockDim.x + threadIdx.x;
    if (i < n4h) bsum[gperm(i)] = bih[i] + bhh[i];
    if (i < nb)  dtv[i] = ts[2 * i + 1] - ts[2 * i];
}

// ---------- GEMM: C[m,n] = sum_k A[m,k]*W[n,k] ----------
// Counted-vmcnt 2-deep prefetch + T2-style granule XOR-swizzle.
// SWIZZLE (rule #21: both-sides-or-neither with global_load_lds): LDS slot (row, kb)
// holds global 16B-granule (row, kb ^ ((row>>1)&3)). Write side: LDS dest linear,
// global source col inverse-swizzled. Read side: ds_read addr applies same involution.
// Bank spread: 16 consecutive rows cover all 8 (row&1,(row>>1)&3) combos -> 2 lanes/bank
// = conflict-free (was 8-way: bank depended only on row parity, 6.3M conflicts/dispatch).
// EPI: 1 = bf16(tanh(acc+bias)) -> outb            (RK4 u)
//      2 = k=acc+bias; S=(first?0:S)+cw*k; ynext=bf16(h+alpha*dt*k)
//      3 = k=acc+bias; outf=f32(h + dt/6*(S+k))    (final ht)
//      4 = fused LSTM cell (gate-interleaved W; writes h bf16 + c f32)
#define BKt 32

template <int EPI, int BM, int BN, bool SPLIT>
__global__ __launch_bounds__(256) void gemm2(
    const unsigned short* __restrict__ A0,   // x part (stride IN_DIM) when SPLIT
    const unsigned short* __restrict__ A1,   // h part (stride H_DIM) / full A
    const unsigned short* __restrict__ W,
    const int M, const int N, const int K,
    const float* __restrict__ bias,
    unsigned short* __restrict__ outb,
    float* __restrict__ outf,
    const float* __restrict__ c_in,          // EPI4: f32 c state
    const unsigned short* __restrict__ hmat, // EPI2/3: bf16 h2
    const float* __restrict__ dtv,
    float* __restrict__ S,
    unsigned short* __restrict__ ynext,
    const float alpha, const float cw, const int first) {
    constexpr int WM = BM / 2;        // rows per wave (2x2 wave grid)
    constexpr int WN = BN / 2;        // cols per wave (must be 64 for EPI4)
    constexpr int MR = WM / 16;
    constexpr int NR = WN / 16;
    constexpr int ALOADS = BM * BKt / 8 / 256;
    constexpr int BLOADS = BN * BKt / 8 / 256;
    constexpr int LIF = ALOADS + BLOADS;

    __shared__ unsigned short lA[2][BM * BKt];
    __shared__ unsigned short lB[2][BN * BKt];
    const int t = threadIdx.x;
    const int lane = t & 63;
    const int wave = t >> 6;
    const int wm = (wave >> 1) * WM;
    const int wn = (wave & 1) * WN;
    const int fr = lane & 15;
    const int kb = lane >> 4;
    const int tile_m = blockIdx.y * BM;
    const int tile_n = blockIdx.x * BN;

    f32x4 acc[MR][NR];
    #pragma unroll
    for (int i = 0; i < MR; ++i)
        #pragma unroll
        for (int j = 0; j < NR; ++j)
            acc[i][j] = (f32x4){0.f, 0.f, 0.f, 0.f};

    const unsigned short* aptr0 = SPLIT ? A0 + (size_t)tile_m * IN_DIM : nullptr;
    const unsigned short* aptr1 = A1 + (size_t)tile_m * (SPLIT ? H_DIM : K);
    const unsigned short* wptr  = W + (size_t)tile_n * K;

    auto stage = [&](int buf, int k0) {
        #pragma unroll
        for (int j = 0; j < ALOADS; ++j) {
            int idx = j * 256 + t;
            int row = idx >> 2;
            // inverse-swizzle the SOURCE granule so linear LDS slot (row, kb4) holds
            // global granule (row, kb4 ^ s); read applies the same XOR.
            int col = ((idx & 3) ^ ((row >> 1) & 3)) * 8;
            const unsigned short* src;
            if constexpr (SPLIT) {
                if (k0 < IN_DIM) src = aptr0 + (size_t)row * IN_DIM + k0 + col;
                else             src = aptr1 + (size_t)row * H_DIM + (k0 - IN_DIM) + col;
            } else {
                src = aptr1 + (size_t)row * K + k0 + col;
            }
            __builtin_amdgcn_global_load_lds(
                (__attribute__((address_space(1))) void*)src,
                (__attribute__((address_space(3))) void*)(&lA[buf][idx * 8]), 16, 0, 0);
        }
        #pragma unroll
        for (int j = 0; j < BLOADS; ++j) {
            int idx = j * 256 + t;
            int row = idx >> 2;
            int col = ((idx & 3) ^ ((row >> 1) & 3)) * 8;
            __builtin_amdgcn_global_load_lds(
                (__attribute__((address_space(1))) void*)(wptr + (size_t)row * K + k0 + col),
                (__attribute__((address_space(3))) void*)(&lB[buf][idx * 8]), 16, 0, 0);
        }
    };

    const int NT = K / BKt;
    stage(0, 0);
    if (NT > 1) stage(1, BKt);
    int cur = 0;
    for (int kt = 0; kt < NT; ++kt) {
        if (kt + 1 < NT) {
            if constexpr (LIF == 2) asm volatile("s_waitcnt vmcnt(2)" ::: "memory");
            else if constexpr (LIF == 3) asm volatile("s_waitcnt vmcnt(3)" ::: "memory");
            else if constexpr (LIF == 4) asm volatile("s_waitcnt vmcnt(4)" ::: "memory");
            else if constexpr (LIF == 6) asm volatile("s_waitcnt vmcnt(6)" ::: "memory");
            else asm volatile("s_waitcnt vmcnt(0)" ::: "memory");
        } else {
            asm volatile("s_waitcnt vmcnt(0)" ::: "memory");
        }
        __builtin_amdgcn_s_barrier();      // all waves' stage(kt) complete
        short8 af[MR], bfr[NR];
        #pragma unroll
        for (int i = 0; i < MR; ++i) {
            const int arow = wm + i * 16 + fr;
            const int akb = kb ^ ((arow >> 1) & 3);   // swizzled read granule
            af[i] = *(const short8*)&lA[cur][arow * BKt + akb * 8];
        }
        #pragma unroll
        for (int j = 0; j < NR; ++j) {
            const int brow = wn + j * 16 + fr;
            const int bkb = kb ^ ((brow >> 1) & 3);
            bfr[j] = *(const short8*)&lB[cur][brow * BKt + bkb * 8];
        }
        #pragma unroll
        for (int i = 0; i < MR; ++i)
            #pragma unroll
            for (int j = 0; j < NR; ++j)
                acc[i][j] = __builtin_amdgcn_mfma_f32_16x16x32_bf16(af[i], bfr[j], acc[i][j], 0, 0, 0);
        asm volatile("" ::: "memory");
        __builtin_amdgcn_s_barrier();      // all waves done reading buf cur
        if (kt + 2 < NT) stage(cur, (kt + 2) * BKt);
        cur ^= 1;
    }

    // epilogue: D element (col = lane&15 -> n, row = (lane>>4)*4+r -> m)
    const int H = N >> 2;                  // EPI4: output width (N = 4H)
    const int jbase = ((tile_n + wn) >> 6) << 4;
    #pragma unroll
    for (int i = 0; i < MR; ++i) {
        #pragma unroll
        for (int r = 0; r < 4; ++r) {
            const int m = tile_m + wm + i * 16 + kb * 4 + r;
            float dt = 0.f;
            if (EPI == 2 || EPI == 3) dt = dtv[m];
            if (EPI == 4) {
                float vg[4];
                #pragma unroll
                for (int g = 0; g < 4; ++g)
                    vg[g] = acc[i][g][r] + bias[tile_n + wn + g * 16 + fr];
                const int j = jbase + fr;
                float cin = c_in[(size_t)m * H + j];
                float ig = sigm(vg[0]);
                float fg = sigm(vg[1]);
                float gg = ftanh(vg[2]);
                float og = sigm(vg[3]);
                float cn = fg * cin + ig * gg;
                float hn = og * ftanh(cn);
                outb[(size_t)m * H + j] = f2bs(hn);   // h (bf16)
                outf[(size_t)m * H + j] = cn;         // c (f32)
            } else {
                #pragma unroll
                for (int j = 0; j < NR; ++j) {
                    const int n = tile_n + wn + j * 16 + fr;
                    const size_t off = (size_t)m * N + n;
                    float v = acc[i][j][r];
                    if (bias) v += bias[n];
                    if (EPI == 1) {
                        outb[off] = f2bs(ftanh(v));
                    } else if (EPI == 2) {
                        float hv = bs2f(hmat[off]);
                        float s = first ? 0.f : S[off];
                        S[off] = s + cw * v;
                        ynext[off] = f2bs(hv + alpha * dt * v);
                    } else { // EPI == 3
                        float hv = bs2f(hmat[off]);
                        outf[off] = hv + (dt * (1.0f / 6.0f)) * (S[off] + v);
                    }
                }
            }
        }
    }
}

// ---------- launch ----------
extern "C" void kernel_launch(void* const* d_in, const int* in_sizes, int n_in,
                              void* d_out, int out_size, void* d_ws, size_t ws_size,
                              hipStream_t stream) {
    int IX = 0, IH0 = 1, IC0 = 2, ITS = 3, IWIH = 4, IWHH = 5, IBIH = 6, IBHH = 7,
        IW1 = 8, IB1 = 9, IW2 = 10, IB2 = 11;
    const bool sorted_ok = n_in >= 12 &&
        in_sizes[0] == 1024 && in_sizes[1] == 1024 && in_sizes[2] == 4096 &&
        in_sizes[3] == 4096 && in_sizes[4] == 4194304 && in_sizes[5] == 4194304 &&
        in_sizes[6] == 2097152 && in_sizes[7] == 8192 && in_sizes[8] == 1048576 &&
        in_sizes[9] == 1048576 && in_sizes[10] == 4194304 && in_sizes[11] == 2097152;
    if (sorted_ok) { // b1,b2,b_hh,b_ih,c0,h0,inputs,ts,w1,w2,w_hh,w_ih
        IB1 = 0; IB2 = 1; IBHH = 2; IBIH = 3; IC0 = 4; IH0 = 5;
        IX = 6; ITS = 7; IW1 = 8; IW2 = 9; IWHH = 10; IWIH = 11;
    }
    const float* x_f   = (const float*)d_in[IX];
    const float* h0_f  = (const float*)d_in[IH0];
    const float* c0_f  = (const float*)d_in[IC0];
    const float* ts_f  = (const float*)d_in[ITS];
    const float* wih_f = (const float*)d_in[IWIH];
    const float* whh_f = (const float*)d_in[IWHH];
    const float* bih_f = (const float*)d_in[IBIH];
    const float* bhh_f = (const float*)d_in[IBHH];
    const float* w1_f  = (const float*)d_in[IW1];
    const float* b1_f  = (const float*)d_in[IB1];
    const float* w2_f  = (const float*)d_in[IW2];
    const float* b2_f  = (const float*)d_in[IB2];

    constexpr size_t SZ_BIN  = (size_t)B_DIM * IN_DIM;       // 2M
    constexpr size_t SZ_BH   = (size_t)B_DIM * H_DIM;        // 4M
    constexpr size_t SZ_HH   = (size_t)H_DIM * H_DIM;        // 1M
    constexpr size_t SZ_WCAT = (size_t)4 * H_DIM * KCAT;     // 6M

    // workspace (~100 MB): f32 regions first, then bf16
    float* bsum = (float*)d_ws;                    // 4H (gate-permuted)
    float* dtv  = bsum + 4 * H_DIM;                // B
    float* S    = dtv + B_DIM;                     // [B,H] f32 (16 MB)
    float* c1f  = S + SZ_BH;                       // [B,H] f32 (16 MB)
    unsigned short* wcat = (unsigned short*)(c1f + SZ_BH);   // [4H,KCAT] interleaved (12 MB)
    unsigned short* w116 = wcat + SZ_WCAT;         // 2 MB
    unsigned short* w216 = w116 + SZ_HH;           // 2 MB
    unsigned short* xb   = w216 + SZ_HH;           // [B,512]  4 MB
    unsigned short* hb0  = xb + SZ_BIN;            // [B,H] 8 MB
    unsigned short* hb1  = hb0 + SZ_BH;            // [B,H] 8 MB
    unsigned short* hb2  = hb1 + SZ_BH;            // [B,H] 8 MB
    unsigned short* ubuf = hb2 + SZ_BH;            // [B,H] 8 MB
    unsigned short* ybuf = ubuf + SZ_BH;           // [B,H] 8 MB

    float* out_ht = (float*)d_out;                 // [B,H] f32
    float* out_c  = out_ht + SZ_BH;                // [B,H] f32

    const int TB = 256;
    pack_all<<<T5 / TB, TB, 0, stream>>>(x_f, h0_f, wih_f, whh_f, w1_f, w2_f,
                                         xb, hb0, wcat, w116, w216);
    prep_small<<<(4 * H_DIM) / TB, TB, 0, stream>>>(bih_f, bhh_f, ts_f, bsum, dtv, 4 * H_DIM, B_DIM);

    dim3 gBig(4 * H_DIM / 128, B_DIM / 128);   // (32,32) = 1024 blocks
    dim3 gSm(H_DIM / 64, B_DIM / 64);          // (16,64) = 1024 blocks

    // cell 1 (fused): gates GEMM + LSTM cell -> h1 (hb1), c1 (c1f). Reads hb0, writes hb1.
    gemm2<4, 128, 128, true><<<gBig, TB, 0, stream>>>(
        xb, hb0, wcat, B_DIM, 4 * H_DIM, KCAT, bsum,
        hb1, c1f, c0_f, nullptr, nullptr, nullptr, nullptr, 0.f, 0.f, 0);
    // cell 2 (fused): reads hb1 + c1f -> h2 (hb2), c2 -> out_c (f32)
    gemm2<4, 128, 128, true><<<gBig, TB, 0, stream>>>(
        xb, hb1, wcat, B_DIM, 4 * H_DIM, KCAT, bsum,
        hb2, out_c, c1f, nullptr, nullptr, nullptr, nullptr, 0.f, 0.f, 0);

    // RK4: f(y) = tanh(y@W1^T+b1)@W2^T + b2
    // stage 1
    gemm2<1, 64, 64, false><<<gSm, TB, 0, stream>>>(
        nullptr, hb2, w116, B_DIM, H_DIM, H_DIM, b1_f,
        ubuf, nullptr, nullptr, nullptr, nullptr, nullptr, nullptr, 0.f, 0.f, 0);
    gemm2<2, 64, 64, false><<<gSm, TB, 0, stream>>>(
        nullptr, ubuf, w216, B_DIM, H_DIM, H_DIM, b2_f,
        nullptr, nullptr, nullptr, hb2, dtv, S, ybuf, 0.5f, 1.0f, 1);
    // stage 2
    gemm2<1, 64, 64, false><<<gSm, TB, 0, stream>>>(
        nullptr, ybuf, w116, B_DIM, H_DIM, H_DIM, b1_f,
        ubuf, nullptr, nullptr, nullptr, nullptr, nullptr, nullptr, 0.f, 0.f, 0);
    gemm2<2, 64, 64, false><<<gSm, TB, 0, stream>>>(
        nullptr, ubuf, w216, B_DIM, H_DIM, H_DIM, b2_f,
        nullptr, nullptr, nullptr, hb2, dtv, S, ybuf, 0.5f, 2.0f, 0);
    // stage 3
    gemm2<1, 64, 64, false><<<gSm, TB, 0, stream>>>(
        nullptr, ybuf, w116, B_DIM, H_DIM, H_DIM, b1_f,
        ubuf, nullptr, nullptr, nullptr, nullptr, nullptr, nullptr, 0.f, 0.f, 0);
    gemm2<2, 64, 64, false><<<gSm, TB, 0, stream>>>(
        nullptr, ubuf, w216, B_DIM, H_DIM, H_DIM, b2_f,
        nullptr, nullptr, nullptr, hb2, dtv, S, ybuf, 1.0f, 2.0f, 0);
    // stage 4 (final): ht -> d_out (f32)
    gemm2<1, 64, 64, false><<<gSm, TB, 0, stream>>>(
        nullptr, ybuf, w116, B_DIM, H_DIM, H_DIM, b1_f,
        ubuf, nullptr, nullptr, nullptr, nullptr, nullptr, nullptr, 0.f, 0.f, 0);
    gemm2<3, 64, 64, false><<<gSm, TB, 0, stream>>>(
        nullptr, ubuf, w216, B_DIM, H_DIM, H_DIM, b2_f,
        nullptr, out_ht, nullptr, hb2, dtv, S, nullptr, 0.f, 0.f, 0);
}

// Round 11
// 338.475 us; speedup vs baseline: 1.7892x; 1.0771x over previous
//
#include <hip/hip_runtime.h>

// ---------- types ----------
typedef short short8 __attribute__((ext_vector_type(8)));     // 8 bf16 bit-patterns (4 VGPRs) - MFMA A/B frag
typedef float f32x4 __attribute__((ext_vector_type(4)));      // MFMA C/D frag
typedef unsigned short u16x8 __attribute__((ext_vector_type(8)));

#define B_DIM 4096
#define IN_DIM 512
#define H_DIM 1024
#define KCAT 1536   // IN_DIM + H_DIM

__device__ __forceinline__ float bs2f(unsigned short s) {
    return __uint_as_float(((unsigned int)s) << 16);
}
__device__ __forceinline__ unsigned short f2bs(float f) {
    unsigned int u = __float_as_uint(f);
    u += 0x7fff + ((u >> 16) & 1);   // RNE
    return (unsigned short)(u >> 16);
}
__device__ __forceinline__ float sigm(float x) { return 1.0f / (1.0f + __expf(-x)); }
__device__ __forceinline__ float ftanh(float x) { return 1.0f - 2.0f / (__expf(2.0f * x) + 1.0f); }

// gate-interleave permutation: orig gate row r (g=r>>10, j=r&1023) -> n' = (j>>4)*64 + g*16 + (j&15)
__device__ __forceinline__ int gperm(int r) {
    int g = r >> 10, j = r & 1023;
    return ((j >> 4) << 6) + (g << 4) + (j & 15);
}

// ---------- fused f32 -> bf16 pack ----------
#define T0 262144    // x    [4096,512]  -> xb flat
#define T1 786432    // h0   [4096,1024] -> hb0 flat
#define T2 1048576   // wih  [4096,512]  -> wcat interleaved rows, col off 0
#define T3 1572864   // whh  [4096,1024] -> wcat interleaved rows, col off 512
#define T4 1703936   // w1   [1024,1024] -> w116 flat
#define T5 1835008   // w2   [1024,1024] -> w216 flat
__device__ __forceinline__ u16x8 cvt8(const float* __restrict__ in, long i) {
    float4 a = *(const float4*)(in + i);
    float4 b = *(const float4*)(in + i + 4);
    u16x8 o;
    o[0] = f2bs(a.x); o[1] = f2bs(a.y); o[2] = f2bs(a.z); o[3] = f2bs(a.w);
    o[4] = f2bs(b.x); o[5] = f2bs(b.y); o[6] = f2bs(b.z); o[7] = f2bs(b.w);
    return o;
}
__global__ __launch_bounds__(256) void pack_all(const float* __restrict__ x,
                                                const float* __restrict__ h0,
                                                const float* __restrict__ wih,
                                                const float* __restrict__ whh,
                                                const float* __restrict__ w1,
                                                const float* __restrict__ w2,
                                                unsigned short* __restrict__ xb,
                                                unsigned short* __restrict__ hb0,
                                                unsigned short* __restrict__ wcat,
                                                unsigned short* __restrict__ w116,
                                                unsigned short* __restrict__ w216) {
    long g = (long)blockIdx.x * 256 + threadIdx.x;
    if (g < T0) {
        long i = g * 8;
        *(u16x8*)(xb + i) = cvt8(x, i);
    } else if (g < T1) {
        long i = (g - T0) * 8;
        *(u16x8*)(hb0 + i) = cvt8(h0, i);
    } else if (g < T2) {
        long i = (g - T1) * 8;
        int r = (int)(i / IN_DIM), c = (int)(i % IN_DIM);
        *(u16x8*)(wcat + (size_t)gperm(r) * KCAT + c) = cvt8(wih, i);
    } else if (g < T3) {
        long i = (g - T2) * 8;
        int r = (int)(i / H_DIM), c = (int)(i % H_DIM);
        *(u16x8*)(wcat + (size_t)gperm(r) * KCAT + IN_DIM + c) = cvt8(whh, i);
    } else if (g < T4) {
        long i = (g - T3) * 8;
        *(u16x8*)(w116 + i) = cvt8(w1, i);
    } else if (g < T5) {
        long i = (g - T4) * 8;
        *(u16x8*)(w216 + i) = cvt8(w2, i);
    }
}

// ---------- bias sum (gate-permuted) + dt ----------
__global__ __launch_bounds__(256) void prep_small(const float* __restrict__ bih,
                                                  const float* __restrict__ bhh,
                                                  const float* __restrict__ ts,
                                                  float* __restrict__ bsum,
                                                  float* __restrict__ dtv,
                                                  int n4h, int nb) {
    int i = blockIdx.x * blockDim.x + threadIdx.x;
    if (i < n4h) bsum[gperm(i)] = bih[i] + bhh[i];
    if (i < nb)  dtv[i] = ts[2 * i + 1] - ts[2 * i];
}

// ================= 8-wave deep-pipelined fused gates kernel =================
// 256x256 tile, BK=32, 512 threads (8 waves, 2M x 4N -> wave tile 128x64).
// 4 LDS buffers (128 KiB total); K-tile kt lives in buf[kt&3]; during kt's two
// phases we stage kt+3 into buf[(kt+3)&3] == buf[(kt-1)&3], which all waves
// finished reading before kt-1's closing barrier -> overwrite is barrier-
// separated (provably race-free). Counted vmcnt certifies own kt+1 loads
// BEFORE the barrier (collective certification via barrier). Never drains to 0
// in steady state; ~3 K-tiles (~2000 cy) of load slack.
// Per phase: {ds_read frags || 2 global_load_lds -> barrier -> setprio(1)
// 16 MFMA setprio(0) -> barrier}. Granule XOR-swizzle (round-10, 0 conflicts).
// Epilogue: fused LSTM cell (gate-interleaved W).
#define NT8 (KCAT / 32)   // 48

__global__ __launch_bounds__(512) void gemm8(
    const unsigned short* __restrict__ xb,   // [B,512]
    const unsigned short* __restrict__ hb,   // [B,1024]
    const unsigned short* __restrict__ W,    // wcat [4096,1536] gate-interleaved
    const float* __restrict__ bias,          // [4096] gate-permuted
    unsigned short* __restrict__ h_out,      // [B,H] bf16
    float* __restrict__ c_out,               // [B,H] f32
    const float* __restrict__ c_in) {        // [B,H] f32
    __shared__ unsigned short lA[4][256 * 32];   // 64 KiB
    __shared__ unsigned short lB[4][256 * 32];   // 64 KiB
    const int t = threadIdx.x;
    const int lane = t & 63;
    const int wave = t >> 6;
    const int wm = (wave >> 2) * 128;   // 0 or 128
    const int wn = (wave & 3) * 64;     // 0,64,128,192
    const int fr = lane & 15;
    const int kb = lane >> 4;
    const int tile_m = blockIdx.y * 256;
    const int tile_n = blockIdx.x * 256;

    f32x4 acc[8][4];
    #pragma unroll
    for (int i = 0; i < 8; ++i)
        #pragma unroll
        for (int j = 0; j < 4; ++j)
            acc[i][j] = (f32x4){0.f, 0.f, 0.f, 0.f};

    auto stageA = [&](int kt) {
        const int buf = kt & 3;
        #pragma unroll
        for (int j = 0; j < 2; ++j) {
            int idx = j * 512 + t;            // 0..1023
            int row = idx >> 2;               // 0..255
            int g = idx & 3;
            int gs = g ^ ((row >> 1) & 3);    // inverse-swizzled source granule
            int kk = kt * 32 + gs * 8;
            const unsigned short* src = (kk < IN_DIM)
                ? xb + (size_t)(tile_m + row) * IN_DIM + kk
                : hb + (size_t)(tile_m + row) * H_DIM + (kk - IN_DIM);
            __builtin_amdgcn_global_load_lds(
                (__attribute__((address_space(1))) void*)src,
                (__attribute__((address_space(3))) void*)(&lA[buf][row * 32 + g * 8]), 16, 0, 0);
        }
    };
    auto stageB = [&](int kt) {
        const int buf = kt & 3;
        #pragma unroll
        for (int j = 0; j < 2; ++j) {
            int idx = j * 512 + t;
            int row = idx >> 2;
            int g = idx & 3;
            int gs = g ^ ((row >> 1) & 3);
            int kk = kt * 32 + gs * 8;
            __builtin_amdgcn_global_load_lds(
                (__attribute__((address_space(1))) void*)(W + (size_t)(tile_n + row) * KCAT + kk),
                (__attribute__((address_space(3))) void*)(&lB[buf][row * 32 + g * 8]), 16, 0, 0);
        }
    };

    // prologue: stage K-tiles 0,1,2 (12 loads/thread); certify own kt0 loads.
    stageA(0); stageB(0);
    stageA(1); stageB(1);
    stageA(2); stageB(2);
    asm volatile("s_waitcnt vmcnt(8)" ::: "memory");
    __builtin_amdgcn_s_barrier();

    for (int kt = 0; kt < NT8; ++kt) {
        const int buf = kt & 3;
        // ---- phase A: B frags + A frags 0-3; stage A-part of kt+3 ----
        short8 bfr[4], af[4];
        #pragma unroll
        for (int j = 0; j < 4; ++j) {
            int brow = wn + j * 16 + fr;
            bfr[j] = *(const short8*)&lB[buf][brow * 32 + (kb ^ ((brow >> 1) & 3)) * 8];
        }
        #pragma unroll
        for (int i = 0; i < 4; ++i) {
            int arow = wm + i * 16 + fr;
            af[i] = *(const short8*)&lA[buf][arow * 32 + (kb ^ ((arow >> 1) & 3)) * 8];
        }
        if (kt + 3 < NT8) stageA(kt + 3);
        __builtin_amdgcn_s_barrier();
        __builtin_amdgcn_s_setprio(1);
        #pragma unroll
        for (int i = 0; i < 4; ++i)
            #pragma unroll
            for (int j = 0; j < 4; ++j)
                acc[i][j] = __builtin_amdgcn_mfma_f32_16x16x32_bf16(af[i], bfr[j], acc[i][j], 0, 0, 0);
        __builtin_amdgcn_s_setprio(0);
        asm volatile("" ::: "memory");
        __builtin_amdgcn_s_barrier();
        // ---- phase B: A frags 4-7; stage B-part of kt+3; certify kt+1 ----
        short8 af2[4];
        #pragma unroll
        for (int i = 0; i < 4; ++i) {
            int arow = wm + 64 + i * 16 + fr;
            af2[i] = *(const short8*)&lA[buf][arow * 32 + (kb ^ ((arow >> 1) & 3)) * 8];
        }
        if (kt + 3 < NT8) stageB(kt + 3);
        if (kt + 3 < NT8)      asm volatile("s_waitcnt vmcnt(8)" ::: "memory");
        else if (kt + 2 < NT8) asm volatile("s_waitcnt vmcnt(4)" ::: "memory");
        else if (kt + 1 < NT8) asm volatile("s_waitcnt vmcnt(0)" ::: "memory");
        __builtin_amdgcn_s_barrier();
        __builtin_amdgcn_s_setprio(1);
        #pragma unroll
        for (int i = 0; i < 4; ++i)
            #pragma unroll
            for (int j = 0; j < 4; ++j)
                acc[4 + i][j] = __builtin_amdgcn_mfma_f32_16x16x32_bf16(af2[i], bfr[j], acc[4 + i][j], 0, 0, 0);
        __builtin_amdgcn_s_setprio(0);
        asm volatile("" ::: "memory");
        __builtin_amdgcn_s_barrier();
    }

    // ---- fused LSTM epilogue (gate-interleaved): lane fr owns all 4 gates of (m,j) ----
    const int jbase = ((tile_n + wn) >> 6) << 4;
    float bv[4];
    #pragma unroll
    for (int g = 0; g < 4; ++g) bv[g] = bias[tile_n + wn + g * 16 + fr];
    #pragma unroll
    for (int i = 0; i < 8; ++i) {
        #pragma unroll
        for (int r = 0; r < 4; ++r) {
            const int m = tile_m + wm + i * 16 + kb * 4 + r;
            const int j = jbase + fr;
            float ig = sigm(acc[i][0][r] + bv[0]);
            float fg = sigm(acc[i][1][r] + bv[1]);
            float gg = ftanh(acc[i][2][r] + bv[2]);
            float og = sigm(acc[i][3][r] + bv[3]);
            float cin = c_in[(size_t)m * H_DIM + j];
            float cn = fg * cin + ig * gg;
            float hn = og * ftanh(cn);
            h_out[(size_t)m * H_DIM + j] = f2bs(hn);
            c_out[(size_t)m * H_DIM + j] = cn;
        }
    }
}

// ---------- RK4 GEMM (round-10 proven): counted-vmcnt 2-deep, 64x64, swizzled ----------
// EPI: 1 = bf16(tanh(acc+bias)) -> outb
//      2 = k=acc+bias; S=(first?0:S)+cw*k; ynext=bf16(h+alpha*dt*k)
//      3 = k=acc+bias; outf=f32(h + dt/6*(S+k))
#define BKt 32

template <int EPI, int BM, int BN>
__global__ __launch_bounds__(256) void gemm2(
    const unsigned short* __restrict__ A1,
    const unsigned short* __restrict__ W,
    const int M, const int N, const int K,
    const float* __restrict__ bias,
    unsigned short* __restrict__ outb,
    float* __restrict__ outf,
    const unsigned short* __restrict__ hmat,
    const float* __restrict__ dtv,
    float* __restrict__ S,
    unsigned short* __restrict__ ynext,
    const float alpha, const float cw, const int first) {
    constexpr int WM = BM / 2;
    constexpr int WN = BN / 2;
    constexpr int MR = WM / 16;
    constexpr int NR = WN / 16;
    constexpr int ALOADS = BM * BKt / 8 / 256;
    constexpr int BLOADS = BN * BKt / 8 / 256;
    constexpr int LIF = ALOADS + BLOADS;

    __shared__ unsigned short lA[2][BM * BKt];
    __shared__ unsigned short lB[2][BN * BKt];
    const int t = threadIdx.x;
    const int lane = t & 63;
    const int wave = t >> 6;
    const int wm = (wave >> 1) * WM;
    const int wn = (wave & 1) * WN;
    const int fr = lane & 15;
    const int kb = lane >> 4;
    const int tile_m = blockIdx.y * BM;
    const int tile_n = blockIdx.x * BN;

    f32x4 acc[MR][NR];
    #pragma unroll
    for (int i = 0; i < MR; ++i)
        #pragma unroll
        for (int j = 0; j < NR; ++j)
            acc[i][j] = (f32x4){0.f, 0.f, 0.f, 0.f};

    const unsigned short* aptr1 = A1 + (size_t)tile_m * K;
    const unsigned short* wptr  = W + (size_t)tile_n * K;

    auto stage = [&](int buf, int k0) {
        #pragma unroll
        for (int j = 0; j < ALOADS; ++j) {
            int idx = j * 256 + t;
            int row = idx >> 2;
            int col = ((idx & 3) ^ ((row >> 1) & 3)) * 8;
            __builtin_amdgcn_global_load_lds(
                (__attribute__((address_space(1))) void*)(aptr1 + (size_t)row * K + k0 + col),
                (__attribute__((address_space(3))) void*)(&lA[buf][idx * 8]), 16, 0, 0);
        }
        #pragma unroll
        for (int j = 0; j < BLOADS; ++j) {
            int idx = j * 256 + t;
            int row = idx >> 2;
            int col = ((idx & 3) ^ ((row >> 1) & 3)) * 8;
            __builtin_amdgcn_global_load_lds(
                (__attribute__((address_space(1))) void*)(wptr + (size_t)row * K + k0 + col),
                (__attribute__((address_space(3))) void*)(&lB[buf][idx * 8]), 16, 0, 0);
        }
    };

    const int NT = K / BKt;
    stage(0, 0);
    if (NT > 1) stage(1, BKt);
    int cur = 0;
    for (int kt = 0; kt < NT; ++kt) {
        if (kt + 1 < NT) {
            if constexpr (LIF == 2) asm volatile("s_waitcnt vmcnt(2)" ::: "memory");
            else if constexpr (LIF == 3) asm volatile("s_waitcnt vmcnt(3)" ::: "memory");
            else if constexpr (LIF == 4) asm volatile("s_waitcnt vmcnt(4)" ::: "memory");
            else asm volatile("s_waitcnt vmcnt(0)" ::: "memory");
        } else {
            asm volatile("s_waitcnt vmcnt(0)" ::: "memory");
        }
        __builtin_amdgcn_s_barrier();
        short8 af[MR], bfr[NR];
        #pragma unroll
        for (int i = 0; i < MR; ++i) {
            const int arow = wm + i * 16 + fr;
            af[i] = *(const short8*)&lA[cur][arow * BKt + (kb ^ ((arow >> 1) & 3)) * 8];
        }
        #pragma unroll
        for (int j = 0; j < NR; ++j) {
            const int brow = wn + j * 16 + fr;
            bfr[j] = *(const short8*)&lB[cur][brow * BKt + (kb ^ ((brow >> 1) & 3)) * 8];
        }
        #pragma unroll
        for (int i = 0; i < MR; ++i)
            #pragma unroll
            for (int j = 0; j < NR; ++j)
                acc[i][j] = __builtin_amdgcn_mfma_f32_16x16x32_bf16(af[i], bfr[j], acc[i][j], 0, 0, 0);
        asm volatile("" ::: "memory");
        __builtin_amdgcn_s_barrier();
        if (kt + 2 < NT) stage(cur, (kt + 2) * BKt);
        cur ^= 1;
    }

    #pragma unroll
    for (int i = 0; i < MR; ++i) {
        #pragma unroll
        for (int r = 0; r < 4; ++r) {
            const int m = tile_m + wm + i * 16 + kb * 4 + r;
            float dt = 0.f;
            if (EPI >= 2) dt = dtv[m];
            #pragma unroll
            for (int j = 0; j < NR; ++j) {
                const int n = tile_n + wn + j * 16 + fr;
                const size_t off = (size_t)m * N + n;
                float v = acc[i][j][r];
                if (bias) v += bias[n];
                if (EPI == 1) {
                    outb[off] = f2bs(ftanh(v));
                } else if (EPI == 2) {
                    float hv = bs2f(hmat[off]);
                    float s = first ? 0.f : S[off];
                    S[off] = s + cw * v;
                    ynext[off] = f2bs(hv + alpha * dt * v);
                } else { // EPI == 3
                    float hv = bs2f(hmat[off]);
                    outf[off] = hv + (dt * (1.0f / 6.0f)) * (S[off] + v);
                }
            }
        }
    }
}

// ---------- launch ----------
extern "C" void kernel_launch(void* const* d_in, const int* in_sizes, int n_in,
                              void* d_out, int out_size, void* d_ws, size_t ws_size,
                              hipStream_t stream) {
    int IX = 0, IH0 = 1, IC0 = 2, ITS = 3, IWIH = 4, IWHH = 5, IBIH = 6, IBHH = 7,
        IW1 = 8, IB1 = 9, IW2 = 10, IB2 = 11;
    const bool sorted_ok = n_in >= 12 &&
        in_sizes[0] == 1024 && in_sizes[1] == 1024 && in_sizes[2] == 4096 &&
        in_sizes[3] == 4096 && in_sizes[4] == 4194304 && in_sizes[5] == 4194304 &&
        in_sizes[6] == 2097152 && in_sizes[7] == 8192 && in_sizes[8] == 1048576 &&
        in_sizes[9] == 1048576 && in_sizes[10] == 4194304 && in_sizes[11] == 2097152;
    if (sorted_ok) { // b1,b2,b_hh,b_ih,c0,h0,inputs,ts,w1,w2,w_hh,w_ih
        IB1 = 0; IB2 = 1; IBHH = 2; IBIH = 3; IC0 = 4; IH0 = 5;
        IX = 6; ITS = 7; IW1 = 8; IW2 = 9; IWHH = 10; IWIH = 11;
    }
    const float* x_f   = (const float*)d_in[IX];
    const float* h0_f  = (const float*)d_in[IH0];
    const float* c0_f  = (const float*)d_in[IC0];
    const float* ts_f  = (const float*)d_in[ITS];
    const float* wih_f = (const float*)d_in[IWIH];
    const float* whh_f = (const float*)d_in[IWHH];
    const float* bih_f = (const float*)d_in[IBIH];
    const float* bhh_f = (const float*)d_in[IBHH];
    const float* w1_f  = (const float*)d_in[IW1];
    const float* b1_f  = (const float*)d_in[IB1];
    const float* w2_f  = (const float*)d_in[IW2];
    const float* b2_f  = (const float*)d_in[IB2];

    constexpr size_t SZ_BIN  = (size_t)B_DIM * IN_DIM;       // 2M
    constexpr size_t SZ_BH   = (size_t)B_DIM * H_DIM;        // 4M
    constexpr size_t SZ_HH   = (size_t)H_DIM * H_DIM;        // 1M
    constexpr size_t SZ_WCAT = (size_t)4 * H_DIM * KCAT;     // 6M

    // workspace (~100 MB): f32 regions first, then bf16
    float* bsum = (float*)d_ws;                    // 4H (gate-permuted)
    float* dtv  = bsum + 4 * H_DIM;                // B
    float* S    = dtv + B_DIM;                     // [B,H] f32 (16 MB)
    float* c1f  = S + SZ_BH;                       // [B,H] f32 (16 MB)
    unsigned short* wcat = (unsigned short*)(c1f + SZ_BH);   // [4H,KCAT] interleaved (12 MB)
    unsigned short* w116 = wcat + SZ_WCAT;         // 2 MB
    unsigned short* w216 = w116 + SZ_HH;           // 2 MB
    unsigned short* xb   = w216 + SZ_HH;           // [B,512]  4 MB
    unsigned short* hb0  = xb + SZ_BIN;            // [B,H] 8 MB
    unsigned short* hb1  = hb0 + SZ_BH;            // [B,H] 8 MB
    unsigned short* hb2  = hb1 + SZ_BH;            // [B,H] 8 MB
    unsigned short* ubuf = hb2 + SZ_BH;            // [B,H] 8 MB
    unsigned short* ybuf = ubuf + SZ_BH;           // [B,H] 8 MB

    float* out_ht = (float*)d_out;                 // [B,H] f32
    float* out_c  = out_ht + SZ_BH;                // [B,H] f32

    const int TB = 256;
    pack_all<<<T5 / TB, TB, 0, stream>>>(x_f, h0_f, wih_f, whh_f, w1_f, w2_f,
                                         xb, hb0, wcat, w116, w216);
    prep_small<<<(4 * H_DIM) / TB, TB, 0, stream>>>(bih_f, bhh_f, ts_f, bsum, dtv, 4 * H_DIM, B_DIM);

    dim3 g8(4 * H_DIM / 256, B_DIM / 256);     // (16,16) = 256 blocks, 512 thr
    dim3 gSm(H_DIM / 64, B_DIM / 64);          // (16,64) = 1024 blocks

    // cell 1 (fused 8-wave): reads xb|hb0 + c0 -> h1 (hb1), c1 (c1f)
    gemm8<<<g8, 512, 0, stream>>>(xb, hb0, wcat, bsum, hb1, c1f, c0_f);
    // cell 2 (fused 8-wave): reads xb|hb1 + c1f -> h2 (hb2), c2 -> out_c (f32)
    gemm8<<<g8, 512, 0, stream>>>(xb, hb1, wcat, bsum, hb2, out_c, c1f);

    // RK4: f(y) = tanh(y@W1^T+b1)@W2^T + b2
    // stage 1
    gemm2<1, 64, 64><<<gSm, TB, 0, stream>>>(
        hb2, w116, B_DIM, H_DIM, H_DIM, b1_f,
        ubuf, nullptr, nullptr, nullptr, nullptr, nullptr, 0.f, 0.f, 0);
    gemm2<2, 64, 64><<<gSm, TB, 0, stream>>>(
        ubuf, w216, B_DIM, H_DIM, H_DIM, b2_f,
        nullptr, nullptr, hb2, dtv, S, ybuf, 0.5f, 1.0f, 1);
    // stage 2
    gemm2<1, 64, 64><<<gSm, TB, 0, stream>>>(
        ybuf, w116, B_DIM, H_DIM, H_DIM, b1_f,
        ubuf, nullptr, nullptr, nullptr, nullptr, nullptr, 0.f, 0.f, 0);
    gemm2<2, 64, 64><<<gSm, TB, 0, stream>>>(
        ubuf, w216, B_DIM, H_DIM, H_DIM, b2_f,
        nullptr, nullptr, hb2, dtv, S, ybuf, 0.5f, 2.0f, 0);
    // stage 3
    gemm2<1, 64, 64><<<gSm, TB, 0, stream>>>(
        ybuf, w116, B_DIM, H_DIM, H_DIM, b1_f,
        ubuf, nullptr, nullptr, nullptr, nullptr, nullptr, 0.f, 0.f, 0);
    gemm2<2, 64, 64><<<gSm, TB, 0, stream>>>(
        ubuf, w216, B_DIM, H_DIM, H_DIM, b2_f,
        nullptr, nullptr, hb2, dtv, S, ybuf, 1.0f, 2.0f, 0);
    // stage 4 (final): ht -> d_out (f32)
    gemm2<1, 64, 64><<<gSm, TB, 0, stream>>>(
        ybuf, w116, B_DIM, H_DIM, H_DIM, b1_f,
        ubuf, nullptr, nullptr, nullptr, nullptr, nullptr, 0.f, 0.f, 0);
    gemm2<3, 64, 64><<<gSm, TB, 0, stream>>>(
        ubuf, w216, B_DIM, H_DIM, H_DIM, b2_f,
        nullptr, out_ht, hb2, dtv, S, nullptr, 0.f, 0.f, 0);
}